// Round 16
// baseline (208.351 us; speedup 1.0000x reference)
//
#include <hip/hip_runtime.h>
#include <math.h>

#define Hh 192
#define Ww 192
#define HWc 36864
#define Bc 4
#define NWc 576
#define NKc 288
#define WNc 24

typedef _Float16 h2_t __attribute__((ext_vector_type(2)));
typedef _Float16 f16x4 __attribute__((ext_vector_type(4)));
typedef float f32x4 __attribute__((ext_vector_type(4)));
typedef unsigned u32x2 __attribute__((ext_vector_type(2)));
__device__ __forceinline__ h2_t u2h(unsigned u) { return __builtin_bit_cast(h2_t, u); }
__device__ __forceinline__ unsigned h2u(h2_t h) { return __builtin_bit_cast(unsigned, h); }
__device__ __forceinline__ h2_t pkrtz(float a, float b) {
    return __builtin_bit_cast(h2_t, __builtin_amdgcn_cvt_pkrtz(a, b));
}
__device__ __forceinline__ f16x4 pk4(float4 v) {
    u32x2 p = { h2u(pkrtz(v.x, v.y)), h2u(pkrtz(v.z, v.w)) };
    return __builtin_bit_cast(f16x4, p);
}
#define L2E 1.44269504f

// ---- K1: q/k/v 1x1 convs, layout [b][y][x][c] ----
// q,k (f16 outputs) via MFMA on f16-quantized x; v via f32 VALU (feeds the
// LayerNorm->score->selection path, which must stay bit-stable).
__global__ __launch_bounds__(256, 1) void k_qkv(const float* __restrict__ x,
    const float* __restrict__ wq, const float* __restrict__ bq,
    const float* __restrict__ wk, const float* __restrict__ bk,
    const float* __restrict__ wvw, const float* __restrict__ bv,
    _Float16* __restrict__ q, _Float16* __restrict__ k, float* __restrict__ v)
{
    __shared__ float xs[132][52];

    int tid = threadIdx.x;
    int blk = blockIdx.x;
    int b = blk / 288;
    int g0 = (blk % 288) * 128;
    const float* xb = x + (size_t)b * 48 * HWc + g0;

    #pragma unroll
    for (int it = 0; it < 24; ++it) {
        int i = it * 256 + tid;
        int c = i >> 7, px = i & 127;
        xs[px][c] = xb[(size_t)c * HWc + px];
    }

    int ln = tid & 63, wave = tid >> 6;
    int dgrp = ln >> 4;

    // v weights (lane = oc)
    float4 Wv[12];
    #pragma unroll
    for (int j = 0; j < 12; ++j) Wv[j] = *(const float4*)(wvw + ln * 48 + j * 4);
    float bvv = bv[ln];

    // q/k A-fragments: A[oc = ln&15 (+16*ot)][ch = dgrp*4+i (+16*ks)]
    f16x4 Aq[4][3], Ak[4][3];
    #pragma unroll
    for (int ot = 0; ot < 4; ++ot)
        #pragma unroll
        for (int ks = 0; ks < 3; ++ks) {
            int oc = ot * 16 + (ln & 15);
            Aq[ot][ks] = pk4(*(const float4*)(wq + oc * 48 + ks * 16 + dgrp * 4));
            Ak[ot][ks] = pk4(*(const float4*)(wk + oc * 48 + ks * 16 + dgrp * 4));
        }
    float4 bqf[4], bkf[4];
    #pragma unroll
    for (int ot = 0; ot < 4; ++ot) {
        bqf[ot] = *(const float4*)(bq + ot * 16 + dgrp * 4);
        bkf[ot] = *(const float4*)(bk + ot * 16 + dgrp * 4);
    }
    __syncthreads();

    size_t pbase = (size_t)b * HWc + g0;

    // ---- v: f32 VALU, 2-deep pipelined, 32 px per wave ----
    {
        int p0 = wave * 32;
        float4 XA[12], XB[12];
        #pragma unroll
        for (int j = 0; j < 12; ++j) XA[j] = *(const float4*)&xs[p0][j * 4];

#define V_COMPUTE(XBUF, PX)                                                    \
        {                                                                      \
            float av = bvv;                                                    \
            _Pragma("unroll")                                                  \
            for (int j = 0; j < 12; ++j) {                                     \
                float4 x4 = XBUF[j];                                           \
                av = fmaf(x4.x, Wv[j].x, av); av = fmaf(x4.y, Wv[j].y, av);    \
                av = fmaf(x4.z, Wv[j].z, av); av = fmaf(x4.w, Wv[j].w, av);    \
            }                                                                  \
            v[(pbase + (size_t)(PX)) * 64 + ln] = av;                          \
        }

        #pragma unroll 1
        for (int i = 0; i < 32; i += 2) {
            int pxA = p0 + i;
            #pragma unroll
            for (int j = 0; j < 12; ++j) XB[j] = *(const float4*)&xs[pxA + 1][j * 4];
            V_COMPUTE(XA, pxA);
            #pragma unroll
            for (int j = 0; j < 12; ++j) XA[j] = *(const float4*)&xs[(pxA + 2) < 128 ? (pxA + 2) : 0][j * 4];
            V_COMPUTE(XB, pxA + 1);
        }
#undef V_COMPUTE
    }

    // ---- q/k via MFMA: wave handles px-tiles 2*wave, 2*wave+1 ----
    #pragma unroll
    for (int t2 = 0; t2 < 2; ++t2) {
        int tn = wave * 2 + t2;
        int px = tn * 16 + (ln & 15);
        f16x4 Bf[3];
        #pragma unroll
        for (int ks = 0; ks < 3; ++ks)
            Bf[ks] = pk4(*(const float4*)&xs[px][ks * 16 + dgrp * 4]);

        #pragma unroll
        for (int ot = 0; ot < 4; ++ot) {
            f32x4 Dq = { bqf[ot].x, bqf[ot].y, bqf[ot].z, bqf[ot].w };
            f32x4 Dk = { bkf[ot].x, bkf[ot].y, bkf[ot].z, bkf[ot].w };
            #pragma unroll
            for (int ks = 0; ks < 3; ++ks) {
                Dq = __builtin_amdgcn_mfma_f32_16x16x16f16(Aq[ot][ks], Bf[ks], Dq, 0, 0, 0);
                Dk = __builtin_amdgcn_mfma_f32_16x16x16f16(Ak[ot][ks], Bf[ks], Dk, 0, 0, 0);
            }
            u32x2 q2 = { h2u(pkrtz(Dq[0], Dq[1])), h2u(pkrtz(Dq[2], Dq[3])) };
            u32x2 k2 = { h2u(pkrtz(Dk[0], Dk[1])), h2u(pkrtz(Dk[2], Dk[3])) };
            size_t off = (pbase + (size_t)px) * 64 + ot * 16 + dgrp * 4;
            *(u32x2*)(q + off) = q2;
            *(u32x2*)(k + off) = k2;
        }
    }
}

// ------- K2: cond conv (68->17) + LayerNorm + leaky + channel-mean -------
__global__ __launch_bounds__(256) void k_cond(const float* __restrict__ vs,
    const float* __restrict__ cg,
    const float* __restrict__ w_in, const float* __restrict__ b_in,
    const float* __restrict__ ln_w, const float* __restrict__ ln_b,
    float* __restrict__ t, float* __restrict__ mpix)
{
    int g = blockIdx.x * 256 + threadIdx.x;
    int b = g / HWc, rem = g % HWc;
    int y = rem / Ww, xx = rem % Ww;

    float in[68];
    const float* vp = vs + (size_t)g * 64;
    #pragma unroll
    for (int c = 0; c < 64; c += 4) {
        float4 t4 = *(const float4*)(vp + c);
        in[c] = t4.x; in[c+1] = t4.y; in[c+2] = t4.z; in[c+3] = t4.w;
    }
    in[64] = cg[((size_t)b * 2 + 0) * HWc + rem];
    in[65] = cg[((size_t)b * 2 + 1) * HWc + rem];
    const float step = 2.0f / 7.0f;
    in[66] = -1.0f + step * (float)(y & 7);
    in[67] = -1.0f + step * (float)(xx & 7);

    float tv[17];
    float mu = 0.f;
    #pragma unroll
    for (int o = 0; o < 17; ++o) {
        float a = b_in[o];
        const float* wr = w_in + o * 68;
        #pragma unroll
        for (int c = 0; c < 68; ++c) a = fmaf(in[c], wr[c], a);
        tv[o] = a;
        mu += a;
    }
    mu *= (1.f / 17.f);
    float var = 0.f;
    #pragma unroll
    for (int o = 0; o < 17; ++o) { float d = tv[o] - mu; var = fmaf(d, d, var); }
    var *= (1.f / 17.f);
    float rstd = 1.f / sqrtf(var + 1e-6f);

    float msum = 0.f;
    #pragma unroll
    for (int o = 0; o < 17; ++o) {
        float z = (tv[o] - mu) * rstd * ln_w[o] + ln_b[o];
        z = (z >= 0.f) ? z : 0.1f * z;
        t[((size_t)b * 17 + o) * HWc + rem] = z;
        msum += z;
    }
    mpix[(size_t)b * HWc + rem] = msum * (1.f / 17.f);
}

// ---------------- K3: 3x3 conv (17->1) + sigmoid ----------------
__global__ __launch_bounds__(256) void k_sa(const float* __restrict__ t,
    const float* __restrict__ w_sa, const float* __restrict__ b_sa,
    float* __restrict__ sa)
{
    int g = blockIdx.x * 256 + threadIdx.x;
    int b = g / HWc, rem = g % HWc;
    int y = rem / Ww, xx = rem % Ww;

    float a = b_sa[0];
    for (int c = 0; c < 17; ++c) {
        const float* tp = t + ((size_t)b * 17 + c) * HWc;
        const float* wr = w_sa + c * 9;
        #pragma unroll
        for (int ki = 0; ki < 3; ++ki) {
            int yy = y + ki - 1;
            if ((unsigned)yy >= 192u) continue;
            #pragma unroll
            for (int kj = 0; kj < 3; ++kj) {
                int xc = xx + kj - 1;
                if ((unsigned)xc >= 192u) continue;
                a = fmaf(tp[yy * Ww + xc], wr[ki * 3 + kj], a);
            }
        }
    }
    sa[g] = 1.f / (1.f + expf(-a));
}

// -- K4: window score MLP + stable descending rank -> compacted lists --
__global__ __launch_bounds__(576) void k_score(const float* __restrict__ mpix,
    const float* __restrict__ w_m1, const float* __restrict__ b_m1,
    const float* __restrict__ w_m2, const float* __restrict__ b_m2,
    int* __restrict__ hardl, int* __restrict__ easyl)
{
    __shared__ float sc[NWc];
    int b = blockIdx.x;
    int w = threadIdx.x;
    {
        int hy = w / WNc, wx = w % WNc;
        const float* mp = mpix + (size_t)b * HWc + (hy * 8) * Ww + wx * 8;
        float m[64];
        #pragma unroll
        for (int l = 0; l < 64; ++l) m[l] = mp[(l >> 3) * Ww + (l & 7)];
        float h1[8];
        #pragma unroll
        for (int j = 0; j < 8; ++j) {
            float a = b_m1[j];
            const float* wr = w_m1 + j * 64;
            #pragma unroll
            for (int l = 0; l < 64; ++l) a = fmaf(m[l], wr[l], a);
            h1[j] = (a >= 0.f) ? a : 0.1f * a;
        }
        float l0 = b_m2[0], l1 = b_m2[1];
        #pragma unroll
        for (int j = 0; j < 8; ++j) {
            l0 = fmaf(h1[j], w_m2[j], l0);
            l1 = fmaf(h1[j], w_m2[8 + j], l1);
        }
        float mx = fmaxf(l0, l1);
        float e0 = expf(l0 - mx), e1 = expf(l1 - mx);
        sc[w] = e0 / (e0 + e1);
    }
    __syncthreads();
    float s = sc[w];
    int cnt = 0;
    for (int w2 = 0; w2 < NWc; ++w2) {
        float s2 = sc[w2];
        cnt += ((s2 > s) || (s2 == s && w2 < w)) ? 1 : 0;
    }
    if (cnt < NKc) hardl[b * NKc + cnt] = w;
    else           easyl[b * NKc + (cnt - NKc)] = w;
}

// ---- K5a: hard windows — MFMA flash attention + MFMA out-conv ----
__global__ __launch_bounds__(256) void k_hard(const _Float16* __restrict__ qs,
    const _Float16* __restrict__ ks, const float* __restrict__ vsb,
    const int* __restrict__ hardl,
    const float* __restrict__ relh, const float* __restrict__ relw,
    const float* __restrict__ w_out, const float* __restrict__ b_out,
    float* __restrict__ out)
{
    __shared__ __align__(16) unsigned char smem[53760];
    unsigned char* Kl  = smem;              // [4][144][16ch f16 =32B], 18432 B
    unsigned char* Vt  = smem + 18432;      // [4][16 d][148 k] f16, 18944 B
    unsigned char* Rel = smem + 37376;      // [4][64 q][32] f16, 16384 B
    _Float16 (*mldsh)[72] = (_Float16 (*)[72])smem;  // 9216 B, aliases Kl

    int tid = threadIdx.x;
    int blk = blockIdx.x;
    int b = blk / NKc;
    int n = hardl[blk];
    int hy = n / WNc, wx = n % WNc;
    int y0 = hy * 8, x0 = wx * 8;

    // ---- stage K (f16 copy) and V (f32->f16, d-major, 148-padded), zero OOB ----
    #pragma unroll
    for (int i = 0; i < 9; ++i) {
        int idx = i * 256 + tid;
        int px = idx >> 4, c4 = idx & 15;
        int py = px / 12, pxx = px - py * 12;
        int ky = y0 - 2 + py, kx = x0 - 2 + pxx;
        bool ok = ((unsigned)ky < 192u) && ((unsigned)kx < 192u);
        int kyc = min(max(ky, 0), 191), kxc = min(max(kx, 0), 191);
        size_t poff = ((size_t)(b * HWc) + kyc * Ww + kxc) * 64 + c4 * 4;
        uint2 k2 = *(const uint2*)(ks + poff);
        float4 v4 = *(const float4*)(vsb + poff);
        if (!ok) { k2 = make_uint2(0, 0); v4 = make_float4(0, 0, 0, 0); }
        int hd = c4 >> 2, d0 = (c4 & 3) * 4;
        *(uint2*)(Kl + hd * 4608 + px * 32 + (c4 & 3) * 8) = k2;
        _Float16* vh = (_Float16*)(Vt + hd * 4736);
        vh[(d0 + 0) * 148 + px] = (_Float16)v4.x;
        vh[(d0 + 1) * 148 + px] = (_Float16)v4.y;
        vh[(d0 + 2) * 148 + px] = (_Float16)v4.z;
        vh[(d0 + 3) * 148 + px] = (_Float16)v4.w;
    }

    int h = __builtin_amdgcn_readfirstlane(tid >> 6);  // head (wave-uniform)
    int l = tid & 63;
    int dgrp = l >> 4;

    // ---- rel tables (log2e-scaled): lane l computes Rw/Rh for query l ----
    {
        int qr = l >> 3, qc = l & 7;
        const _Float16* qp = qs + ((size_t)(b * HWc) + (y0 + qr) * Ww + (x0 + qc)) * 64 + h * 16;
        uint4 q0 = *(const uint4*)qp;
        uint4 q1 = *(const uint4*)(qp + 8);
        h2_t qhp[8] = { u2h(q0.x), u2h(q0.y), u2h(q0.z), u2h(q0.w),
                        u2h(q1.x), u2h(q1.y), u2h(q1.z), u2h(q1.w) };
        float qv[16];
        #pragma unroll
        for (int j = 0; j < 8; ++j) { qv[2*j] = (float)qhp[j].x; qv[2*j+1] = (float)qhp[j].y; }

        float rw[12], rh[12];
        #pragma unroll
        for (int kc = 0; kc < 12; ++kc) {
            const float* rp = relw + (kc - qc + 11) * 16;
            float a = 0.f;
            #pragma unroll
            for (int j = 0; j < 4; ++j) {
                float4 t4 = *(const float4*)(rp + j * 4);
                a = fmaf(qv[j*4+0], t4.x, a); a = fmaf(qv[j*4+1], t4.y, a);
                a = fmaf(qv[j*4+2], t4.z, a); a = fmaf(qv[j*4+3], t4.w, a);
            }
            rw[kc] = a;
        }
        #pragma unroll
        for (int kr = 0; kr < 12; ++kr) {
            const float* rp = relh + (kr - qr + 11) * 16;
            float a = 0.f;
            #pragma unroll
            for (int j = 0; j < 4; ++j) {
                float4 t4 = *(const float4*)(rp + j * 4);
                a = fmaf(qv[j*4+0], t4.x, a); a = fmaf(qv[j*4+1], t4.y, a);
                a = fmaf(qv[j*4+2], t4.z, a); a = fmaf(qv[j*4+3], t4.w, a);
            }
            rh[kr] = a;
        }
        unsigned rr[16];
        #pragma unroll
        for (int j = 0; j < 6; ++j) rr[j]     = h2u(pkrtz(L2E * rw[2*j], L2E * rw[2*j+1]));
        #pragma unroll
        for (int j = 0; j < 6; ++j) rr[6 + j] = h2u(pkrtz(L2E * rh[2*j], L2E * rh[2*j+1]));
        rr[12] = rr[13] = rr[14] = rr[15] = 0u;
        uint4* dst = (uint4*)(Rel + h * 4096 + l * 64);
        dst[0] = make_uint4(rr[0], rr[1], rr[2],  rr[3]);
        dst[1] = make_uint4(rr[4], rr[5], rr[6],  rr[7]);
        dst[2] = make_uint4(rr[8], rr[9], rr[10], rr[11]);
        dst[3] = make_uint4(rr[12], rr[13], rr[14], rr[15]);
    }
    __syncthreads();

    // ---- B-fragments (persist): Q scaled by 0.25*log2e, rel step1/step2 ----
    f16x4 qb[4], rb1[4], rb2[4];
    {
        const h2_t qsc = { (_Float16)(0.25f * L2E), (_Float16)(0.25f * L2E) };
        #pragma unroll
        for (int tn = 0; tn < 4; ++tn) {
            int q = tn * 16 + (l & 15);
            int qr = q >> 3, qc = q & 7;
            uint2 raw = *(const uint2*)(qs + ((size_t)(b * HWc) + (y0 + qr) * Ww + (x0 + qc)) * 64 + h * 16 + dgrp * 4);
            h2_t lo = u2h(raw.x) * qsc, hi = u2h(raw.y) * qsc;
            u32x2 packed = { h2u(lo), h2u(hi) };
            qb[tn] = __builtin_bit_cast(f16x4, packed);
            const unsigned char* rbase = Rel + h * 4096 + q * 64 + dgrp * 8;
            rb1[tn] = *(const f16x4*)rbase;
            rb2[tn] = *(const f16x4*)(rbase + 32);
        }
    }

    // ---- main loop over 9 key tiles, 2-deep ka/va prefetch ----
    f32x4 Oacc[4];
    float lsum[4];
    #pragma unroll
    for (int tn = 0; tn < 4; ++tn) { Oacc[tn] = (f32x4){0.f,0.f,0.f,0.f}; lsum[tn] = 0.f; }
    const f32x4 zf = {0.f, 0.f, 0.f, 0.f};
    const float SH = 3.0f * L2E;

    f16x4 kaA = *(const f16x4*)(Kl + h * 4608 + (l & 15) * 32 + dgrp * 8);
    f16x4 vaA = *(const f16x4*)(Vt + h * 4736 + (l & 15) * 296 + (dgrp * 4) * 2);

    #pragma unroll 1
    for (int tm = 0; tm < 9; ++tm) {
        int tmn = (tm + 1 < 9) ? tm + 1 : 0;
        f16x4 kaB = *(const f16x4*)(Kl + h * 4608 + (tmn * 16 + (l & 15)) * 32 + dgrp * 8);
        f16x4 vaB = *(const f16x4*)(Vt + h * 4736 + (l & 15) * 296 + (tmn * 16 + dgrp * 4) * 2);

        int key = tm * 16 + (l & 15);
        int kr = (key * 2731) >> 15;
        int kc = key - kr * 12;
        f16x4 oh1, oh2;
        #pragma unroll
        for (int i = 0; i < 4; ++i) {
            int a1 = 4 * dgrp + i;
            bool v1 = (a1 < 12) ? (kc == a1) : (kr == a1 - 12);
            oh1[i] = v1 ? (_Float16)1.0f : (_Float16)0.0f;
            int a2 = 16 + 4 * dgrp + i;
            bool v2 = (a2 < 24) && (kr == a2 - 12);
            oh2[i] = v2 ? (_Float16)1.0f : (_Float16)0.0f;
        }

        #pragma unroll
        for (int tn = 0; tn < 4; ++tn) {
            f32x4 s = __builtin_amdgcn_mfma_f32_16x16x16f16(kaA, qb[tn],  zf, 0, 0, 0);
            s       = __builtin_amdgcn_mfma_f32_16x16x16f16(oh1, rb1[tn], s,  0, 0, 0);
            s       = __builtin_amdgcn_mfma_f32_16x16x16f16(oh2, rb2[tn], s,  0, 0, 0);
            float e0 = exp2f(s[0] - SH);
            float e1 = exp2f(s[1] - SH);
            float e2 = exp2f(s[2] - SH);
            float e3 = exp2f(s[3] - SH);
            lsum[tn] += (e0 + e1) + (e2 + e3);
            u32x2 pp = { h2u(pkrtz(e0, e1)), h2u(pkrtz(e2, e3)) };
            f16x4 pb = __builtin_bit_cast(f16x4, pp);
            Oacc[tn] = __builtin_amdgcn_mfma_f32_16x16x16f16(vaA, pb, Oacc[tn], 0, 0, 0);
        }
        kaA = kaB; vaA = vaB;
    }

    // ---- normalize + write f16 to mldsh (aliases Kl) ----
    __syncthreads();
    #pragma unroll
    for (int tn = 0; tn < 4; ++tn) {
        float s = lsum[tn];
        s += __shfl_xor(s, 16);
        s += __shfl_xor(s, 32);
        float inv = 1.f / s;
        int q = tn * 16 + (l & 15);
        u32x2 w2 = { h2u(pkrtz(Oacc[tn][0] * inv, Oacc[tn][1] * inv)),
                     h2u(pkrtz(Oacc[tn][2] * inv, Oacc[tn][3] * inv)) };
        *(u32x2*)&mldsh[q][h * 16 + dgrp * 4] = w2;
    }
    __syncthreads();

    // ---- fused out-conv via MFMA: D[48oc x 64px] = w_out(f16) . mldsh ----
    {
        int tn2 = h;
        int pxl = tn2 * 16 + (l & 15);
        f16x4 bf[4];
        #pragma unroll
        for (int ks = 0; ks < 4; ++ks)
            bf[ks] = *(const f16x4*)&mldsh[pxl][ks * 16 + dgrp * 4];

        int gy = y0 + (pxl >> 3), gx = x0 + (pxl & 7);
        #pragma unroll
        for (int ot = 0; ot < 3; ++ot) {
            float4 bi = *(const float4*)(b_out + ot * 16 + dgrp * 4);
            f32x4 Cacc = { bi.x, bi.y, bi.z, bi.w };
            #pragma unroll
            for (int ks = 0; ks < 4; ++ks) {
                float4 wv = *(const float4*)(w_out + (ot * 16 + (l & 15)) * 64 + ks * 16 + dgrp * 4);
                Cacc = __builtin_amdgcn_mfma_f32_16x16x16f16(pk4(wv), bf[ks], Cacc, 0, 0, 0);
            }
            #pragma unroll
            for (int i = 0; i < 4; ++i)
                out[((size_t)(b * 48 + ot * 16 + dgrp * 4 + i)) * HWc + gy * Ww + gx] = Cacc[i];
        }
    }
}

// ---- K5b: easy windows — vs*sa (f16) + MFMA out-conv ----
__global__ __launch_bounds__(256) void k_easy(const float* __restrict__ vsb,
    const float* __restrict__ sab, const int* __restrict__ easyl,
    const float* __restrict__ w_out, const float* __restrict__ b_out,
    float* __restrict__ out)
{
    __shared__ __align__(16) _Float16 mldsh[64][72];   // 9216 B

    int tid = threadIdx.x;
    int blk = blockIdx.x;
    int b = blk / NKc;
    int n = easyl[blk];
    int hy = n / WNc, wx = n % WNc;
    int y0 = hy * 8, x0 = wx * 8;

    {
        int l = tid >> 2, part = tid & 3;
        int gy = y0 + (l >> 3), gx = x0 + (l & 7);
        const float* vp = vsb + ((size_t)(b * HWc) + gy * Ww + gx) * 64 + part * 16;
        float sv = sab[(size_t)b * HWc + gy * Ww + gx];
        #pragma unroll
        for (int j = 0; j < 4; ++j) {
            float4 v4 = *(const float4*)(vp + j * 4);
            u32x2 w2 = { h2u(pkrtz(v4.x * sv, v4.y * sv)),
                         h2u(pkrtz(v4.z * sv, v4.w * sv)) };
            *(u32x2*)&mldsh[l][part * 16 + j * 4] = w2;
        }
    }
    __syncthreads();

    {
        int l = tid & 63;
        int tn2 = __builtin_amdgcn_readfirstlane(tid >> 6);
        int dgrp = l >> 4;
        int pxl = tn2 * 16 + (l & 15);
        f16x4 bf[4];
        #pragma unroll
        for (int ks = 0; ks < 4; ++ks)
            bf[ks] = *(const f16x4*)&mldsh[pxl][ks * 16 + dgrp * 4];

        int gy = y0 + (pxl >> 3), gx = x0 + (pxl & 7);
        #pragma unroll
        for (int ot = 0; ot < 3; ++ot) {
            float4 bi = *(const float4*)(b_out + ot * 16 + dgrp * 4);
            f32x4 Cacc = { bi.x, bi.y, bi.z, bi.w };
            #pragma unroll
            for (int ks = 0; ks < 4; ++ks) {
                float4 wv = *(const float4*)(w_out + (ot * 16 + (l & 15)) * 64 + ks * 16 + dgrp * 4);
                Cacc = __builtin_amdgcn_mfma_f32_16x16x16f16(pk4(wv), bf[ks], Cacc, 0, 0, 0);
            }
            #pragma unroll
            for (int i = 0; i < 4; ++i)
                out[((size_t)(b * 48 + ot * 16 + dgrp * 4 + i)) * HWc + gy * Ww + gx] = Cacc[i];
        }
    }
}

extern "C" void kernel_launch(void* const* d_in, const int* in_sizes, int n_in,
                              void* d_out, int out_size, void* d_ws, size_t ws_size,
                              hipStream_t stream)
{
    const float* x    = (const float*)d_in[0];
    const float* cg   = (const float*)d_in[1];
    const float* wq   = (const float*)d_in[2];
    const float* bq   = (const float*)d_in[3];
    const float* wk   = (const float*)d_in[4];
    const float* bk   = (const float*)d_in[5];
    const float* wv   = (const float*)d_in[6];
    const float* bv   = (const float*)d_in[7];
    const float* w_in = (const float*)d_in[8];
    const float* b_in = (const float*)d_in[9];
    const float* ln_w = (const float*)d_in[10];
    const float* ln_b = (const float*)d_in[11];
    const float* w_sa = (const float*)d_in[12];
    const float* b_sa = (const float*)d_in[13];
    const float* w_m1 = (const float*)d_in[14];
    const float* b_m1 = (const float*)d_in[15];
    const float* w_m2 = (const float*)d_in[16];
    const float* b_m2 = (const float*)d_in[17];
    const float* rel_h= (const float*)d_in[18];
    const float* rel_w= (const float*)d_in[19];
    const float* w_out= (const float*)d_in[20];
    const float* b_out= (const float*)d_in[21];
    float* out = (float*)d_out;

    _Float16* qsh = (_Float16*)d_ws;
    _Float16* ksh = qsh + (size_t)Bc * 64 * HWc;
    float* vs   = (float*)(ksh + (size_t)Bc * 64 * HWc);
    float* t    = vs + (size_t)Bc * 64 * HWc;
    float* sa   = t  + (size_t)Bc * 17 * HWc;
    float* mpix = sa + (size_t)Bc * HWc;
    int*   hardl= (int*)(mpix + (size_t)Bc * HWc);
    int*   easyl= hardl + Bc * NKc;

    k_qkv  <<<1152, 256, 0, stream>>>(x, wq, bq, wk, bk, wv, bv, qsh, ksh, vs);
    k_cond <<<576, 256, 0, stream>>>(vs, cg, w_in, b_in, ln_w, ln_b, t, mpix);
    k_sa   <<<576, 256, 0, stream>>>(t, w_sa, b_sa, sa);
    k_score<<<4, 576, 0, stream>>>(mpix, w_m1, b_m1, w_m2, b_m2, hardl, easyl);
    k_easy <<<1152, 256, 0, stream>>>(vs, sa, easyl, w_out, b_out, out);
    k_hard <<<1152, 256, 0, stream>>>(qsh, ksh, vs, hardl, rel_h, rel_w, w_out, b_out, out);
}

// Round 17
// 202.208 us; speedup vs baseline: 1.0304x; 1.0304x over previous
//
#include <hip/hip_runtime.h>
#include <math.h>

#define Hh 192
#define Ww 192
#define HWc 36864
#define Bc 4
#define NWc 576
#define NKc 288
#define WNc 24

typedef _Float16 h2_t __attribute__((ext_vector_type(2)));
typedef _Float16 f16x4 __attribute__((ext_vector_type(4)));
typedef float f32x4 __attribute__((ext_vector_type(4)));
typedef unsigned u32x2 __attribute__((ext_vector_type(2)));
__device__ __forceinline__ h2_t u2h(unsigned u) { return __builtin_bit_cast(h2_t, u); }
__device__ __forceinline__ unsigned h2u(h2_t h) { return __builtin_bit_cast(unsigned, h); }
__device__ __forceinline__ h2_t pkrtz(float a, float b) {
    return __builtin_bit_cast(h2_t, __builtin_amdgcn_cvt_pkrtz(a, b));
}
__device__ __forceinline__ f16x4 pk4(float4 v) {
    u32x2 p = { h2u(pkrtz(v.x, v.y)), h2u(pkrtz(v.z, v.w)) };
    return __builtin_bit_cast(f16x4, p);
}
#define L2E 1.44269504f

// ---- K1: q/k/v 1x1 convs, layout [b][y][x][c] ----
// Sections are sequenced (q/k MFMA first, then v VALU) so their register
// live-ranges don't overlap: R16's combined version hit VGPR=152 which
// crossed the 128-reg occupancy quantum and halved resident waves.
__global__ __launch_bounds__(256, 1) void k_qkv(const float* __restrict__ x,
    const float* __restrict__ wq, const float* __restrict__ bq,
    const float* __restrict__ wk, const float* __restrict__ bk,
    const float* __restrict__ wvw, const float* __restrict__ bv,
    _Float16* __restrict__ q, _Float16* __restrict__ k, float* __restrict__ v)
{
    __shared__ float xs[132][52];

    int tid = threadIdx.x;
    int blk = blockIdx.x;
    int b = blk / 288;
    int g0 = (blk % 288) * 128;
    const float* xb = x + (size_t)b * 48 * HWc + g0;

    #pragma unroll
    for (int it = 0; it < 24; ++it) {
        int i = it * 256 + tid;
        int c = i >> 7, px = i & 127;
        xs[px][c] = xb[(size_t)c * HWc + px];
    }

    int ln = tid & 63, wave = tid >> 6;
    int dgrp = ln >> 4;
    __syncthreads();

    size_t pbase = (size_t)b * HWc + g0;

    // ---- section 1: q/k via MFMA (scoped; regs release before v) ----
    {
        f16x4 Aq[4][3], Ak[4][3];
        #pragma unroll
        for (int ot = 0; ot < 4; ++ot)
            #pragma unroll
            for (int ks = 0; ks < 3; ++ks) {
                int oc = ot * 16 + (ln & 15);
                Aq[ot][ks] = pk4(*(const float4*)(wq + oc * 48 + ks * 16 + dgrp * 4));
                Ak[ot][ks] = pk4(*(const float4*)(wk + oc * 48 + ks * 16 + dgrp * 4));
            }
        float4 bqf[4], bkf[4];
        #pragma unroll
        for (int ot = 0; ot < 4; ++ot) {
            bqf[ot] = *(const float4*)(bq + ot * 16 + dgrp * 4);
            bkf[ot] = *(const float4*)(bk + ot * 16 + dgrp * 4);
        }

        #pragma unroll
        for (int t2 = 0; t2 < 2; ++t2) {
            int tn = wave * 2 + t2;
            int px = tn * 16 + (ln & 15);
            f16x4 Bf[3];
            #pragma unroll
            for (int ks = 0; ks < 3; ++ks)
                Bf[ks] = pk4(*(const float4*)&xs[px][ks * 16 + dgrp * 4]);

            #pragma unroll
            for (int ot = 0; ot < 4; ++ot) {
                f32x4 Dq = { bqf[ot].x, bqf[ot].y, bqf[ot].z, bqf[ot].w };
                f32x4 Dk = { bkf[ot].x, bkf[ot].y, bkf[ot].z, bkf[ot].w };
                #pragma unroll
                for (int ks = 0; ks < 3; ++ks) {
                    Dq = __builtin_amdgcn_mfma_f32_16x16x16f16(Aq[ot][ks], Bf[ks], Dq, 0, 0, 0);
                    Dk = __builtin_amdgcn_mfma_f32_16x16x16f16(Ak[ot][ks], Bf[ks], Dk, 0, 0, 0);
                }
                u32x2 q2 = { h2u(pkrtz(Dq[0], Dq[1])), h2u(pkrtz(Dq[2], Dq[3])) };
                u32x2 k2 = { h2u(pkrtz(Dk[0], Dk[1])), h2u(pkrtz(Dk[2], Dk[3])) };
                size_t off = (pbase + (size_t)px) * 64 + ot * 16 + dgrp * 4;
                *(u32x2*)(q + off) = q2;
                *(u32x2*)(k + off) = k2;
            }
        }
    }

    // ---- section 2: v via f32 VALU, 4-px chained ILP (scoped weights) ----
    {
        float4 Wv[12];
        #pragma unroll
        for (int j = 0; j < 12; ++j) Wv[j] = *(const float4*)(wvw + ln * 48 + j * 4);
        float bvv = bv[ln];

        int p0 = wave * 32;
        #pragma unroll 1
        for (int g4 = 0; g4 < 8; ++g4) {
            int px = p0 + g4 * 4;
            float a0 = bvv, a1 = bvv, a2 = bvv, a3 = bvv;
            #pragma unroll
            for (int j = 0; j < 12; ++j) {
                float4 x0 = *(const float4*)&xs[px + 0][j * 4];
                float4 x1 = *(const float4*)&xs[px + 1][j * 4];
                float4 x2 = *(const float4*)&xs[px + 2][j * 4];
                float4 x3 = *(const float4*)&xs[px + 3][j * 4];
                a0 = fmaf(x0.x, Wv[j].x, a0); a0 = fmaf(x0.y, Wv[j].y, a0);
                a0 = fmaf(x0.z, Wv[j].z, a0); a0 = fmaf(x0.w, Wv[j].w, a0);
                a1 = fmaf(x1.x, Wv[j].x, a1); a1 = fmaf(x1.y, Wv[j].y, a1);
                a1 = fmaf(x1.z, Wv[j].z, a1); a1 = fmaf(x1.w, Wv[j].w, a1);
                a2 = fmaf(x2.x, Wv[j].x, a2); a2 = fmaf(x2.y, Wv[j].y, a2);
                a2 = fmaf(x2.z, Wv[j].z, a2); a2 = fmaf(x2.w, Wv[j].w, a2);
                a3 = fmaf(x3.x, Wv[j].x, a3); a3 = fmaf(x3.y, Wv[j].y, a3);
                a3 = fmaf(x3.z, Wv[j].z, a3); a3 = fmaf(x3.w, Wv[j].w, a3);
            }
            v[(pbase + (size_t)(px + 0)) * 64 + ln] = a0;
            v[(pbase + (size_t)(px + 1)) * 64 + ln] = a1;
            v[(pbase + (size_t)(px + 2)) * 64 + ln] = a2;
            v[(pbase + (size_t)(px + 3)) * 64 + ln] = a3;
        }
    }
}

// ------- K2: cond conv (68->17) + LayerNorm + leaky + channel-mean -------
__global__ __launch_bounds__(256) void k_cond(const float* __restrict__ vs,
    const float* __restrict__ cg,
    const float* __restrict__ w_in, const float* __restrict__ b_in,
    const float* __restrict__ ln_w, const float* __restrict__ ln_b,
    float* __restrict__ t, float* __restrict__ mpix)
{
    int g = blockIdx.x * 256 + threadIdx.x;
    int b = g / HWc, rem = g % HWc;
    int y = rem / Ww, xx = rem % Ww;

    float in[68];
    const float* vp = vs + (size_t)g * 64;
    #pragma unroll
    for (int c = 0; c < 64; c += 4) {
        float4 t4 = *(const float4*)(vp + c);
        in[c] = t4.x; in[c+1] = t4.y; in[c+2] = t4.z; in[c+3] = t4.w;
    }
    in[64] = cg[((size_t)b * 2 + 0) * HWc + rem];
    in[65] = cg[((size_t)b * 2 + 1) * HWc + rem];
    const float step = 2.0f / 7.0f;
    in[66] = -1.0f + step * (float)(y & 7);
    in[67] = -1.0f + step * (float)(xx & 7);

    float tv[17];
    float mu = 0.f;
    #pragma unroll
    for (int o = 0; o < 17; ++o) {
        float a = b_in[o];
        const float* wr = w_in + o * 68;
        #pragma unroll
        for (int c = 0; c < 68; ++c) a = fmaf(in[c], wr[c], a);
        tv[o] = a;
        mu += a;
    }
    mu *= (1.f / 17.f);
    float var = 0.f;
    #pragma unroll
    for (int o = 0; o < 17; ++o) { float d = tv[o] - mu; var = fmaf(d, d, var); }
    var *= (1.f / 17.f);
    float rstd = 1.f / sqrtf(var + 1e-6f);

    float msum = 0.f;
    #pragma unroll
    for (int o = 0; o < 17; ++o) {
        float z = (tv[o] - mu) * rstd * ln_w[o] + ln_b[o];
        z = (z >= 0.f) ? z : 0.1f * z;
        t[((size_t)b * 17 + o) * HWc + rem] = z;
        msum += z;
    }
    mpix[(size_t)b * HWc + rem] = msum * (1.f / 17.f);
}

// ---------------- K3: 3x3 conv (17->1) + sigmoid ----------------
__global__ __launch_bounds__(256) void k_sa(const float* __restrict__ t,
    const float* __restrict__ w_sa, const float* __restrict__ b_sa,
    float* __restrict__ sa)
{
    int g = blockIdx.x * 256 + threadIdx.x;
    int b = g / HWc, rem = g % HWc;
    int y = rem / Ww, xx = rem % Ww;

    float a = b_sa[0];
    for (int c = 0; c < 17; ++c) {
        const float* tp = t + ((size_t)b * 17 + c) * HWc;
        const float* wr = w_sa + c * 9;
        #pragma unroll
        for (int ki = 0; ki < 3; ++ki) {
            int yy = y + ki - 1;
            if ((unsigned)yy >= 192u) continue;
            #pragma unroll
            for (int kj = 0; kj < 3; ++kj) {
                int xc = xx + kj - 1;
                if ((unsigned)xc >= 192u) continue;
                a = fmaf(tp[yy * Ww + xc], wr[ki * 3 + kj], a);
            }
        }
    }
    sa[g] = 1.f / (1.f + expf(-a));
}

// -- K4: window score MLP + stable descending rank -> compacted lists --
__global__ __launch_bounds__(576) void k_score(const float* __restrict__ mpix,
    const float* __restrict__ w_m1, const float* __restrict__ b_m1,
    const float* __restrict__ w_m2, const float* __restrict__ b_m2,
    int* __restrict__ hardl, int* __restrict__ easyl)
{
    __shared__ float sc[NWc];
    int b = blockIdx.x;
    int w = threadIdx.x;
    {
        int hy = w / WNc, wx = w % WNc;
        const float* mp = mpix + (size_t)b * HWc + (hy * 8) * Ww + wx * 8;
        float m[64];
        #pragma unroll
        for (int l = 0; l < 64; ++l) m[l] = mp[(l >> 3) * Ww + (l & 7)];
        float h1[8];
        #pragma unroll
        for (int j = 0; j < 8; ++j) {
            float a = b_m1[j];
            const float* wr = w_m1 + j * 64;
            #pragma unroll
            for (int l = 0; l < 64; ++l) a = fmaf(m[l], wr[l], a);
            h1[j] = (a >= 0.f) ? a : 0.1f * a;
        }
        float l0 = b_m2[0], l1 = b_m2[1];
        #pragma unroll
        for (int j = 0; j < 8; ++j) {
            l0 = fmaf(h1[j], w_m2[j], l0);
            l1 = fmaf(h1[j], w_m2[8 + j], l1);
        }
        float mx = fmaxf(l0, l1);
        float e0 = expf(l0 - mx), e1 = expf(l1 - mx);
        sc[w] = e0 / (e0 + e1);
    }
    __syncthreads();
    float s = sc[w];
    int cnt = 0;
    for (int w2 = 0; w2 < NWc; ++w2) {
        float s2 = sc[w2];
        cnt += ((s2 > s) || (s2 == s && w2 < w)) ? 1 : 0;
    }
    if (cnt < NKc) hardl[b * NKc + cnt] = w;
    else           easyl[b * NKc + (cnt - NKc)] = w;
}

// ---- K5a: hard windows — MFMA flash attention + MFMA out-conv ----
__global__ __launch_bounds__(256) void k_hard(const _Float16* __restrict__ qs,
    const _Float16* __restrict__ ks, const float* __restrict__ vsb,
    const int* __restrict__ hardl,
    const float* __restrict__ relh, const float* __restrict__ relw,
    const float* __restrict__ w_out, const float* __restrict__ b_out,
    float* __restrict__ out)
{
    __shared__ __align__(16) unsigned char smem[53760];
    unsigned char* Kl  = smem;              // [4][144][16ch f16 =32B], 18432 B
    unsigned char* Vt  = smem + 18432;      // [4][16 d][148 k] f16, 18944 B
    unsigned char* Rel = smem + 37376;      // [4][64 q][32] f16, 16384 B
    _Float16 (*mldsh)[72] = (_Float16 (*)[72])smem;  // 9216 B, aliases Kl

    int tid = threadIdx.x;
    int blk = blockIdx.x;
    int b = blk / NKc;
    int n = hardl[blk];
    int hy = n / WNc, wx = n % WNc;
    int y0 = hy * 8, x0 = wx * 8;

    // ---- stage K (f16 copy) and V (f32->f16, d-major, 148-padded), zero OOB ----
    #pragma unroll
    for (int i = 0; i < 9; ++i) {
        int idx = i * 256 + tid;
        int px = idx >> 4, c4 = idx & 15;
        int py = px / 12, pxx = px - py * 12;
        int ky = y0 - 2 + py, kx = x0 - 2 + pxx;
        bool ok = ((unsigned)ky < 192u) && ((unsigned)kx < 192u);
        int kyc = min(max(ky, 0), 191), kxc = min(max(kx, 0), 191);
        size_t poff = ((size_t)(b * HWc) + kyc * Ww + kxc) * 64 + c4 * 4;
        uint2 k2 = *(const uint2*)(ks + poff);
        float4 v4 = *(const float4*)(vsb + poff);
        if (!ok) { k2 = make_uint2(0, 0); v4 = make_float4(0, 0, 0, 0); }
        int hd = c4 >> 2, d0 = (c4 & 3) * 4;
        *(uint2*)(Kl + hd * 4608 + px * 32 + (c4 & 3) * 8) = k2;
        _Float16* vh = (_Float16*)(Vt + hd * 4736);
        vh[(d0 + 0) * 148 + px] = (_Float16)v4.x;
        vh[(d0 + 1) * 148 + px] = (_Float16)v4.y;
        vh[(d0 + 2) * 148 + px] = (_Float16)v4.z;
        vh[(d0 + 3) * 148 + px] = (_Float16)v4.w;
    }

    int h = __builtin_amdgcn_readfirstlane(tid >> 6);  // head (wave-uniform)
    int l = tid & 63;
    int dgrp = l >> 4;

    // ---- rel tables (log2e-scaled): lane l computes Rw/Rh for query l ----
    {
        int qr = l >> 3, qc = l & 7;
        const _Float16* qp = qs + ((size_t)(b * HWc) + (y0 + qr) * Ww + (x0 + qc)) * 64 + h * 16;
        uint4 q0 = *(const uint4*)qp;
        uint4 q1 = *(const uint4*)(qp + 8);
        h2_t qhp[8] = { u2h(q0.x), u2h(q0.y), u2h(q0.z), u2h(q0.w),
                        u2h(q1.x), u2h(q1.y), u2h(q1.z), u2h(q1.w) };
        float qv[16];
        #pragma unroll
        for (int j = 0; j < 8; ++j) { qv[2*j] = (float)qhp[j].x; qv[2*j+1] = (float)qhp[j].y; }

        float rw[12], rh[12];
        #pragma unroll
        for (int kc = 0; kc < 12; ++kc) {
            const float* rp = relw + (kc - qc + 11) * 16;
            float a = 0.f;
            #pragma unroll
            for (int j = 0; j < 4; ++j) {
                float4 t4 = *(const float4*)(rp + j * 4);
                a = fmaf(qv[j*4+0], t4.x, a); a = fmaf(qv[j*4+1], t4.y, a);
                a = fmaf(qv[j*4+2], t4.z, a); a = fmaf(qv[j*4+3], t4.w, a);
            }
            rw[kc] = a;
        }
        #pragma unroll
        for (int kr = 0; kr < 12; ++kr) {
            const float* rp = relh + (kr - qr + 11) * 16;
            float a = 0.f;
            #pragma unroll
            for (int j = 0; j < 4; ++j) {
                float4 t4 = *(const float4*)(rp + j * 4);
                a = fmaf(qv[j*4+0], t4.x, a); a = fmaf(qv[j*4+1], t4.y, a);
                a = fmaf(qv[j*4+2], t4.z, a); a = fmaf(qv[j*4+3], t4.w, a);
            }
            rh[kr] = a;
        }
        unsigned rr[16];
        #pragma unroll
        for (int j = 0; j < 6; ++j) rr[j]     = h2u(pkrtz(L2E * rw[2*j], L2E * rw[2*j+1]));
        #pragma unroll
        for (int j = 0; j < 6; ++j) rr[6 + j] = h2u(pkrtz(L2E * rh[2*j], L2E * rh[2*j+1]));
        rr[12] = rr[13] = rr[14] = rr[15] = 0u;
        uint4* dst = (uint4*)(Rel + h * 4096 + l * 64);
        dst[0] = make_uint4(rr[0], rr[1], rr[2],  rr[3]);
        dst[1] = make_uint4(rr[4], rr[5], rr[6],  rr[7]);
        dst[2] = make_uint4(rr[8], rr[9], rr[10], rr[11]);
        dst[3] = make_uint4(rr[12], rr[13], rr[14], rr[15]);
    }
    __syncthreads();

    // ---- B-fragments (persist): Q scaled by 0.25*log2e, rel step1/step2 ----
    f16x4 qb[4], rb1[4], rb2[4];
    {
        const h2_t qsc = { (_Float16)(0.25f * L2E), (_Float16)(0.25f * L2E) };
        #pragma unroll
        for (int tn = 0; tn < 4; ++tn) {
            int q = tn * 16 + (l & 15);
            int qr = q >> 3, qc = q & 7;
            uint2 raw = *(const uint2*)(qs + ((size_t)(b * HWc) + (y0 + qr) * Ww + (x0 + qc)) * 64 + h * 16 + dgrp * 4);
            h2_t lo = u2h(raw.x) * qsc, hi = u2h(raw.y) * qsc;
            u32x2 packed = { h2u(lo), h2u(hi) };
            qb[tn] = __builtin_bit_cast(f16x4, packed);
            const unsigned char* rbase = Rel + h * 4096 + q * 64 + dgrp * 8;
            rb1[tn] = *(const f16x4*)rbase;
            rb2[tn] = *(const f16x4*)(rbase + 32);
        }
    }

    // ---- main loop over 9 key tiles, 2-deep ka/va prefetch ----
    f32x4 Oacc[4];
    float lsum[4];
    #pragma unroll
    for (int tn = 0; tn < 4; ++tn) { Oacc[tn] = (f32x4){0.f,0.f,0.f,0.f}; lsum[tn] = 0.f; }
    const f32x4 zf = {0.f, 0.f, 0.f, 0.f};
    const float SH = 3.0f * L2E;

    f16x4 kaA = *(const f16x4*)(Kl + h * 4608 + (l & 15) * 32 + dgrp * 8);
    f16x4 vaA = *(const f16x4*)(Vt + h * 4736 + (l & 15) * 296 + (dgrp * 4) * 2);

    #pragma unroll 1
    for (int tm = 0; tm < 9; ++tm) {
        int tmn = (tm + 1 < 9) ? tm + 1 : 0;
        f16x4 kaB = *(const f16x4*)(Kl + h * 4608 + (tmn * 16 + (l & 15)) * 32 + dgrp * 8);
        f16x4 vaB = *(const f16x4*)(Vt + h * 4736 + (l & 15) * 296 + (tmn * 16 + dgrp * 4) * 2);

        int key = tm * 16 + (l & 15);
        int kr = (key * 2731) >> 15;
        int kc = key - kr * 12;
        f16x4 oh1, oh2;
        #pragma unroll
        for (int i = 0; i < 4; ++i) {
            int a1 = 4 * dgrp + i;
            bool v1 = (a1 < 12) ? (kc == a1) : (kr == a1 - 12);
            oh1[i] = v1 ? (_Float16)1.0f : (_Float16)0.0f;
            int a2 = 16 + 4 * dgrp + i;
            bool v2 = (a2 < 24) && (kr == a2 - 12);
            oh2[i] = v2 ? (_Float16)1.0f : (_Float16)0.0f;
        }

        #pragma unroll
        for (int tn = 0; tn < 4; ++tn) {
            f32x4 s = __builtin_amdgcn_mfma_f32_16x16x16f16(kaA, qb[tn],  zf, 0, 0, 0);
            s       = __builtin_amdgcn_mfma_f32_16x16x16f16(oh1, rb1[tn], s,  0, 0, 0);
            s       = __builtin_amdgcn_mfma_f32_16x16x16f16(oh2, rb2[tn], s,  0, 0, 0);
            float e0 = exp2f(s[0] - SH);
            float e1 = exp2f(s[1] - SH);
            float e2 = exp2f(s[2] - SH);
            float e3 = exp2f(s[3] - SH);
            lsum[tn] += (e0 + e1) + (e2 + e3);
            u32x2 pp = { h2u(pkrtz(e0, e1)), h2u(pkrtz(e2, e3)) };
            f16x4 pb = __builtin_bit_cast(f16x4, pp);
            Oacc[tn] = __builtin_amdgcn_mfma_f32_16x16x16f16(vaA, pb, Oacc[tn], 0, 0, 0);
        }
        kaA = kaB; vaA = vaB;
    }

    // ---- normalize + write f16 to mldsh (aliases Kl) ----
    __syncthreads();
    #pragma unroll
    for (int tn = 0; tn < 4; ++tn) {
        float s = lsum[tn];
        s += __shfl_xor(s, 16);
        s += __shfl_xor(s, 32);
        float inv = 1.f / s;
        int q = tn * 16 + (l & 15);
        u32x2 w2 = { h2u(pkrtz(Oacc[tn][0] * inv, Oacc[tn][1] * inv)),
                     h2u(pkrtz(Oacc[tn][2] * inv, Oacc[tn][3] * inv)) };
        *(u32x2*)&mldsh[q][h * 16 + dgrp * 4] = w2;
    }
    __syncthreads();

    // ---- fused out-conv via MFMA: D[48oc x 64px] = w_out(f16) . mldsh ----
    {
        int tn2 = h;
        int pxl = tn2 * 16 + (l & 15);
        f16x4 bf[4];
        #pragma unroll
        for (int ks = 0; ks < 4; ++ks)
            bf[ks] = *(const f16x4*)&mldsh[pxl][ks * 16 + dgrp * 4];

        int gy = y0 + (pxl >> 3), gx = x0 + (pxl & 7);
        #pragma unroll
        for (int ot = 0; ot < 3; ++ot) {
            float4 bi = *(const float4*)(b_out + ot * 16 + dgrp * 4);
            f32x4 Cacc = { bi.x, bi.y, bi.z, bi.w };
            #pragma unroll
            for (int ks = 0; ks < 4; ++ks) {
                float4 wv = *(const float4*)(w_out + (ot * 16 + (l & 15)) * 64 + ks * 16 + dgrp * 4);
                Cacc = __builtin_amdgcn_mfma_f32_16x16x16f16(pk4(wv), bf[ks], Cacc, 0, 0, 0);
            }
            #pragma unroll
            for (int i = 0; i < 4; ++i)
                out[((size_t)(b * 48 + ot * 16 + dgrp * 4 + i)) * HWc + gy * Ww + gx] = Cacc[i];
        }
    }
}

// ---- K5b: easy windows — vs*sa (f16) + MFMA out-conv ----
__global__ __launch_bounds__(256) void k_easy(const float* __restrict__ vsb,
    const float* __restrict__ sab, const int* __restrict__ easyl,
    const float* __restrict__ w_out, const float* __restrict__ b_out,
    float* __restrict__ out)
{
    __shared__ __align__(16) _Float16 mldsh[64][72];   // 9216 B

    int tid = threadIdx.x;
    int blk = blockIdx.x;
    int b = blk / NKc;
    int n = easyl[blk];
    int hy = n / WNc, wx = n % WNc;
    int y0 = hy * 8, x0 = wx * 8;

    {
        int l = tid >> 2, part = tid & 3;
        int gy = y0 + (l >> 3), gx = x0 + (l & 7);
        const float* vp = vsb + ((size_t)(b * HWc) + gy * Ww + gx) * 64 + part * 16;
        float sv = sab[(size_t)b * HWc + gy * Ww + gx];
        #pragma unroll
        for (int j = 0; j < 4; ++j) {
            float4 v4 = *(const float4*)(vp + j * 4);
            u32x2 w2 = { h2u(pkrtz(v4.x * sv, v4.y * sv)),
                         h2u(pkrtz(v4.z * sv, v4.w * sv)) };
            *(u32x2*)&mldsh[l][part * 16 + j * 4] = w2;
        }
    }
    __syncthreads();

    {
        int l = tid & 63;
        int tn2 = __builtin_amdgcn_readfirstlane(tid >> 6);
        int dgrp = l >> 4;
        int pxl = tn2 * 16 + (l & 15);
        f16x4 bf[4];
        #pragma unroll
        for (int ks = 0; ks < 4; ++ks)
            bf[ks] = *(const f16x4*)&mldsh[pxl][ks * 16 + dgrp * 4];

        int gy = y0 + (pxl >> 3), gx = x0 + (pxl & 7);
        #pragma unroll
        for (int ot = 0; ot < 3; ++ot) {
            float4 bi = *(const float4*)(b_out + ot * 16 + dgrp * 4);
            f32x4 Cacc = { bi.x, bi.y, bi.z, bi.w };
            #pragma unroll
            for (int ks = 0; ks < 4; ++ks) {
                float4 wv = *(const float4*)(w_out + (ot * 16 + (l & 15)) * 64 + ks * 16 + dgrp * 4);
                Cacc = __builtin_amdgcn_mfma_f32_16x16x16f16(pk4(wv), bf[ks], Cacc, 0, 0, 0);
            }
            #pragma unroll
            for (int i = 0; i < 4; ++i)
                out[((size_t)(b * 48 + ot * 16 + dgrp * 4 + i)) * HWc + gy * Ww + gx] = Cacc[i];
        }
    }
}

extern "C" void kernel_launch(void* const* d_in, const int* in_sizes, int n_in,
                              void* d_out, int out_size, void* d_ws, size_t ws_size,
                              hipStream_t stream)
{
    const float* x    = (const float*)d_in[0];
    const float* cg   = (const float*)d_in[1];
    const float* wq   = (const float*)d_in[2];
    const float* bq   = (const float*)d_in[3];
    const float* wk   = (const float*)d_in[4];
    const float* bk   = (const float*)d_in[5];
    const float* wv   = (const float*)d_in[6];
    const float* bv   = (const float*)d_in[7];
    const float* w_in = (const float*)d_in[8];
    const float* b_in = (const float*)d_in[9];
    const float* ln_w = (const float*)d_in[10];
    const float* ln_b = (const float*)d_in[11];
    const float* w_sa = (const float*)d_in[12];
    const float* b_sa = (const float*)d_in[13];
    const float* w_m1 = (const float*)d_in[14];
    const float* b_m1 = (const float*)d_in[15];
    const float* w_m2 = (const float*)d_in[16];
    const float* b_m2 = (const float*)d_in[17];
    const float* rel_h= (const float*)d_in[18];
    const float* rel_w= (const float*)d_in[19];
    const float* w_out= (const float*)d_in[20];
    const float* b_out= (const float*)d_in[21];
    float* out = (float*)d_out;

    _Float16* qsh = (_Float16*)d_ws;
    _Float16* ksh = qsh + (size_t)Bc * 64 * HWc;
    float* vs   = (float*)(ksh + (size_t)Bc * 64 * HWc);
    float* t    = vs + (size_t)Bc * 64 * HWc;
    float* sa   = t  + (size_t)Bc * 17 * HWc;
    float* mpix = sa + (size_t)Bc * HWc;
    int*   hardl= (int*)(mpix + (size_t)Bc * HWc);
    int*   easyl= hardl + Bc * NKc;

    k_qkv  <<<1152, 256, 0, stream>>>(x, wq, bq, wk, bk, wv, bv, qsh, ksh, vs);
    k_cond <<<576, 256, 0, stream>>>(vs, cg, w_in, b_in, ln_w, ln_b, t, mpix);
    k_sa   <<<576, 256, 0, stream>>>(t, w_sa, b_sa, sa);
    k_score<<<4, 576, 0, stream>>>(mpix, w_m1, b_m1, w_m2, b_m2, hardl, easyl);
    k_easy <<<1152, 256, 0, stream>>>(vs, sa, easyl, w_out, b_out, out);
    k_hard <<<1152, 256, 0, stream>>>(qsh, ksh, vs, hardl, rel_h, rel_w, w_out, b_out, out);
}

// Round 18
// 193.474 us; speedup vs baseline: 1.0769x; 1.0451x over previous
//
#include <hip/hip_runtime.h>
#include <math.h>

#define Hh 192
#define Ww 192
#define HWc 36864
#define Bc 4
#define NWc 576
#define NKc 288
#define WNc 24

typedef _Float16 h2_t __attribute__((ext_vector_type(2)));
typedef _Float16 f16x4 __attribute__((ext_vector_type(4)));
typedef float f32x4 __attribute__((ext_vector_type(4)));
typedef unsigned u32x2 __attribute__((ext_vector_type(2)));
__device__ __forceinline__ h2_t u2h(unsigned u) { return __builtin_bit_cast(h2_t, u); }
__device__ __forceinline__ unsigned h2u(h2_t h) { return __builtin_bit_cast(unsigned, h); }
__device__ __forceinline__ h2_t pkrtz(float a, float b) {
    return __builtin_bit_cast(h2_t, __builtin_amdgcn_cvt_pkrtz(a, b));
}
__device__ __forceinline__ f16x4 pk4(float4 v) {
    u32x2 p = { h2u(pkrtz(v.x, v.y)), h2u(pkrtz(v.z, v.w)) };
    return __builtin_bit_cast(f16x4, p);
}
#define L2E 1.44269504f

// ---- K1: q/k/v 1x1 convs, layout [b][y][x][c] ----
__global__ __launch_bounds__(256, 1) void k_qkv(const float* __restrict__ x,
    const float* __restrict__ wq, const float* __restrict__ bq,
    const float* __restrict__ wk, const float* __restrict__ bk,
    const float* __restrict__ wvw, const float* __restrict__ bv,
    _Float16* __restrict__ q, _Float16* __restrict__ k, float* __restrict__ v)
{
    __shared__ float xs[132][52];

    int tid = threadIdx.x;
    int blk = blockIdx.x;
    int b = blk / 288;
    int g0 = (blk % 288) * 128;
    const float* xb = x + (size_t)b * 48 * HWc + g0;

    #pragma unroll
    for (int it = 0; it < 24; ++it) {
        int i = it * 256 + tid;
        int c = i >> 7, px = i & 127;
        xs[px][c] = xb[(size_t)c * HWc + px];
    }

    int ln = tid & 63, wave = tid >> 6;
    int dgrp = ln >> 4;
    __syncthreads();

    size_t pbase = (size_t)b * HWc + g0;

    // ---- section 1: q/k via MFMA (scoped; regs release before v) ----
    {
        f16x4 Aq[4][3], Ak[4][3];
        #pragma unroll
        for (int ot = 0; ot < 4; ++ot)
            #pragma unroll
            for (int ks = 0; ks < 3; ++ks) {
                int oc = ot * 16 + (ln & 15);
                Aq[ot][ks] = pk4(*(const float4*)(wq + oc * 48 + ks * 16 + dgrp * 4));
                Ak[ot][ks] = pk4(*(const float4*)(wk + oc * 48 + ks * 16 + dgrp * 4));
            }
        float4 bqf[4], bkf[4];
        #pragma unroll
        for (int ot = 0; ot < 4; ++ot) {
            bqf[ot] = *(const float4*)(bq + ot * 16 + dgrp * 4);
            bkf[ot] = *(const float4*)(bk + ot * 16 + dgrp * 4);
        }

        #pragma unroll
        for (int t2 = 0; t2 < 2; ++t2) {
            int tn = wave * 2 + t2;
            int px = tn * 16 + (ln & 15);
            f16x4 Bf[3];
            #pragma unroll
            for (int ks = 0; ks < 3; ++ks)
                Bf[ks] = pk4(*(const float4*)&xs[px][ks * 16 + dgrp * 4]);

            #pragma unroll
            for (int ot = 0; ot < 4; ++ot) {
                f32x4 Dq = { bqf[ot].x, bqf[ot].y, bqf[ot].z, bqf[ot].w };
                f32x4 Dk = { bkf[ot].x, bkf[ot].y, bkf[ot].z, bkf[ot].w };
                #pragma unroll
                for (int ks = 0; ks < 3; ++ks) {
                    Dq = __builtin_amdgcn_mfma_f32_16x16x16f16(Aq[ot][ks], Bf[ks], Dq, 0, 0, 0);
                    Dk = __builtin_amdgcn_mfma_f32_16x16x16f16(Ak[ot][ks], Bf[ks], Dk, 0, 0, 0);
                }
                u32x2 q2 = { h2u(pkrtz(Dq[0], Dq[1])), h2u(pkrtz(Dq[2], Dq[3])) };
                u32x2 k2 = { h2u(pkrtz(Dk[0], Dk[1])), h2u(pkrtz(Dk[2], Dk[3])) };
                size_t off = (pbase + (size_t)px) * 64 + ot * 16 + dgrp * 4;
                *(u32x2*)(q + off) = q2;
                *(u32x2*)(k + off) = k2;
            }
        }
    }

    // ---- section 2: v via f32 VALU, 4-px chained ILP (scoped weights) ----
    {
        float4 Wv[12];
        #pragma unroll
        for (int j = 0; j < 12; ++j) Wv[j] = *(const float4*)(wvw + ln * 48 + j * 4);
        float bvv = bv[ln];

        int p0 = wave * 32;
        #pragma unroll 1
        for (int g4 = 0; g4 < 8; ++g4) {
            int px = p0 + g4 * 4;
            float a0 = bvv, a1 = bvv, a2 = bvv, a3 = bvv;
            #pragma unroll
            for (int j = 0; j < 12; ++j) {
                float4 x0 = *(const float4*)&xs[px + 0][j * 4];
                float4 x1 = *(const float4*)&xs[px + 1][j * 4];
                float4 x2 = *(const float4*)&xs[px + 2][j * 4];
                float4 x3 = *(const float4*)&xs[px + 3][j * 4];
                a0 = fmaf(x0.x, Wv[j].x, a0); a0 = fmaf(x0.y, Wv[j].y, a0);
                a0 = fmaf(x0.z, Wv[j].z, a0); a0 = fmaf(x0.w, Wv[j].w, a0);
                a1 = fmaf(x1.x, Wv[j].x, a1); a1 = fmaf(x1.y, Wv[j].y, a1);
                a1 = fmaf(x1.z, Wv[j].z, a1); a1 = fmaf(x1.w, Wv[j].w, a1);
                a2 = fmaf(x2.x, Wv[j].x, a2); a2 = fmaf(x2.y, Wv[j].y, a2);
                a2 = fmaf(x2.z, Wv[j].z, a2); a2 = fmaf(x2.w, Wv[j].w, a2);
                a3 = fmaf(x3.x, Wv[j].x, a3); a3 = fmaf(x3.y, Wv[j].y, a3);
                a3 = fmaf(x3.z, Wv[j].z, a3); a3 = fmaf(x3.w, Wv[j].w, a3);
            }
            v[(pbase + (size_t)(px + 0)) * 64 + ln] = a0;
            v[(pbase + (size_t)(px + 1)) * 64 + ln] = a1;
            v[(pbase + (size_t)(px + 2)) * 64 + ln] = a2;
            v[(pbase + (size_t)(px + 3)) * 64 + ln] = a3;
        }
    }
}

// -- K2: FUSED cond conv (68->17) + LayerNorm + leaky + mpix + 3x3 conv + sigmoid --
// Block = one image row (192 threads). t rows y-1..y+1 computed into LDS
// (3x recompute across blocks, bit-identical math) -> t never hits HBM and
// the 3x3 conv's 153 strided global loads become LDS reads.
__global__ __launch_bounds__(192) void k_condsa(const float* __restrict__ vs,
    const float* __restrict__ cg,
    const float* __restrict__ w_in, const float* __restrict__ b_in,
    const float* __restrict__ ln_w, const float* __restrict__ ln_b,
    const float* __restrict__ w_sa, const float* __restrict__ b_sa,
    float* __restrict__ sa, float* __restrict__ mpix)
{
    __shared__ float tl[3][17][194];   // 39.5 KB

    int px = threadIdx.x;              // 0..191
    int blk = blockIdx.x;
    int b = blk / Hh;
    int y = blk % Hh;
    const float step = 2.0f / 7.0f;
    float gx_in = -1.0f + step * (float)(px & 7);

    #pragma unroll 1
    for (int r = 0; r < 3; ++r) {
        int yy = y - 1 + r;
        if ((unsigned)yy >= 192u) continue;
        size_t prem = (size_t)yy * Ww + px;

        float in[68];
        const float* vp = vs + ((size_t)b * HWc + prem) * 64;
        #pragma unroll
        for (int c = 0; c < 64; c += 4) {
            float4 t4 = *(const float4*)(vp + c);
            in[c] = t4.x; in[c+1] = t4.y; in[c+2] = t4.z; in[c+3] = t4.w;
        }
        in[64] = cg[((size_t)b * 2 + 0) * HWc + prem];
        in[65] = cg[((size_t)b * 2 + 1) * HWc + prem];
        in[66] = -1.0f + step * (float)(yy & 7);
        in[67] = gx_in;

        float tv[17];
        float mu = 0.f;
        #pragma unroll
        for (int o = 0; o < 17; ++o) {
            float a = b_in[o];
            const float* wr = w_in + o * 68;
            #pragma unroll
            for (int c = 0; c < 68; ++c) a = fmaf(in[c], wr[c], a);
            tv[o] = a;
            mu += a;
        }
        mu *= (1.f / 17.f);
        float var = 0.f;
        #pragma unroll
        for (int o = 0; o < 17; ++o) { float d = tv[o] - mu; var = fmaf(d, d, var); }
        var *= (1.f / 17.f);
        float rstd = 1.f / sqrtf(var + 1e-6f);

        float msum = 0.f;
        #pragma unroll
        for (int o = 0; o < 17; ++o) {
            float z = (tv[o] - mu) * rstd * ln_w[o] + ln_b[o];
            z = (z >= 0.f) ? z : 0.1f * z;
            tl[r][o][px] = z;
            msum += z;
        }
        if (r == 1) mpix[(size_t)b * HWc + prem] = msum * (1.f / 17.f);
    }
    __syncthreads();

    // 3x3 conv over LDS tile + sigmoid
    float a = b_sa[0];
    #pragma unroll 1
    for (int c = 0; c < 17; ++c) {
        const float* wr = w_sa + c * 9;
        #pragma unroll
        for (int ki = 0; ki < 3; ++ki) {
            int yy = y + ki - 1;
            if ((unsigned)yy >= 192u) continue;
            #pragma unroll
            for (int kj = 0; kj < 3; ++kj) {
                int xc = px + kj - 1;
                if ((unsigned)xc >= 192u) continue;
                a = fmaf(tl[ki][c][xc], wr[ki * 3 + kj], a);
            }
        }
    }
    sa[(size_t)b * HWc + (size_t)y * Ww + px] = 1.f / (1.f + expf(-a));
}

// -- K4: window score MLP + stable descending rank -> compacted lists --
__global__ __launch_bounds__(576) void k_score(const float* __restrict__ mpix,
    const float* __restrict__ w_m1, const float* __restrict__ b_m1,
    const float* __restrict__ w_m2, const float* __restrict__ b_m2,
    int* __restrict__ hardl, int* __restrict__ easyl)
{
    __shared__ float sc[NWc];
    int b = blockIdx.x;
    int w = threadIdx.x;
    {
        int hy = w / WNc, wx = w % WNc;
        const float* mp = mpix + (size_t)b * HWc + (hy * 8) * Ww + wx * 8;
        float m[64];
        #pragma unroll
        for (int l = 0; l < 64; ++l) m[l] = mp[(l >> 3) * Ww + (l & 7)];
        float h1[8];
        #pragma unroll
        for (int j = 0; j < 8; ++j) {
            float a = b_m1[j];
            const float* wr = w_m1 + j * 64;
            #pragma unroll
            for (int l = 0; l < 64; ++l) a = fmaf(m[l], wr[l], a);
            h1[j] = (a >= 0.f) ? a : 0.1f * a;
        }
        float l0 = b_m2[0], l1 = b_m2[1];
        #pragma unroll
        for (int j = 0; j < 8; ++j) {
            l0 = fmaf(h1[j], w_m2[j], l0);
            l1 = fmaf(h1[j], w_m2[8 + j], l1);
        }
        float mx = fmaxf(l0, l1);
        float e0 = expf(l0 - mx), e1 = expf(l1 - mx);
        sc[w] = e0 / (e0 + e1);
    }
    __syncthreads();
    float s = sc[w];
    int cnt = 0;
    for (int w2 = 0; w2 < NWc; ++w2) {
        float s2 = sc[w2];
        cnt += ((s2 > s) || (s2 == s && w2 < w)) ? 1 : 0;
    }
    if (cnt < NKc) hardl[b * NKc + cnt] = w;
    else           easyl[b * NKc + (cnt - NKc)] = w;
}

// ---- K5a: hard windows — MFMA flash attention + MFMA out-conv ----
__global__ __launch_bounds__(256) void k_hard(const _Float16* __restrict__ qs,
    const _Float16* __restrict__ ks, const float* __restrict__ vsb,
    const int* __restrict__ hardl,
    const float* __restrict__ relh, const float* __restrict__ relw,
    const float* __restrict__ w_out, const float* __restrict__ b_out,
    float* __restrict__ out)
{
    __shared__ __align__(16) unsigned char smem[53760];
    unsigned char* Kl  = smem;              // [4][144][16ch f16 =32B], 18432 B
    unsigned char* Vt  = smem + 18432;      // [4][16 d][148 k] f16, 18944 B
    unsigned char* Rel = smem + 37376;      // [4][64 q][32] f16, 16384 B
    _Float16 (*mldsh)[72] = (_Float16 (*)[72])smem;  // 9216 B, aliases Kl

    int tid = threadIdx.x;
    int blk = blockIdx.x;
    int b = blk / NKc;
    int n = hardl[blk];
    int hy = n / WNc, wx = n % WNc;
    int y0 = hy * 8, x0 = wx * 8;

    // ---- stage K (f16 copy) and V (f32->f16, d-major, 148-padded), zero OOB ----
    #pragma unroll
    for (int i = 0; i < 9; ++i) {
        int idx = i * 256 + tid;
        int px = idx >> 4, c4 = idx & 15;
        int py = px / 12, pxx = px - py * 12;
        int ky = y0 - 2 + py, kx = x0 - 2 + pxx;
        bool ok = ((unsigned)ky < 192u) && ((unsigned)kx < 192u);
        int kyc = min(max(ky, 0), 191), kxc = min(max(kx, 0), 191);
        size_t poff = ((size_t)(b * HWc) + kyc * Ww + kxc) * 64 + c4 * 4;
        uint2 k2 = *(const uint2*)(ks + poff);
        float4 v4 = *(const float4*)(vsb + poff);
        if (!ok) { k2 = make_uint2(0, 0); v4 = make_float4(0, 0, 0, 0); }
        int hd = c4 >> 2, d0 = (c4 & 3) * 4;
        *(uint2*)(Kl + hd * 4608 + px * 32 + (c4 & 3) * 8) = k2;
        _Float16* vh = (_Float16*)(Vt + hd * 4736);
        vh[(d0 + 0) * 148 + px] = (_Float16)v4.x;
        vh[(d0 + 1) * 148 + px] = (_Float16)v4.y;
        vh[(d0 + 2) * 148 + px] = (_Float16)v4.z;
        vh[(d0 + 3) * 148 + px] = (_Float16)v4.w;
    }

    int h = __builtin_amdgcn_readfirstlane(tid >> 6);  // head (wave-uniform)
    int l = tid & 63;
    int dgrp = l >> 4;

    // ---- rel tables (log2e-scaled): lane l computes Rw/Rh for query l ----
    {
        int qr = l >> 3, qc = l & 7;
        const _Float16* qp = qs + ((size_t)(b * HWc) + (y0 + qr) * Ww + (x0 + qc)) * 64 + h * 16;
        uint4 q0 = *(const uint4*)qp;
        uint4 q1 = *(const uint4*)(qp + 8);
        h2_t qhp[8] = { u2h(q0.x), u2h(q0.y), u2h(q0.z), u2h(q0.w),
                        u2h(q1.x), u2h(q1.y), u2h(q1.z), u2h(q1.w) };
        float qv[16];
        #pragma unroll
        for (int j = 0; j < 8; ++j) { qv[2*j] = (float)qhp[j].x; qv[2*j+1] = (float)qhp[j].y; }

        float rw[12], rh[12];
        #pragma unroll
        for (int kc = 0; kc < 12; ++kc) {
            const float* rp = relw + (kc - qc + 11) * 16;
            float a = 0.f;
            #pragma unroll
            for (int j = 0; j < 4; ++j) {
                float4 t4 = *(const float4*)(rp + j * 4);
                a = fmaf(qv[j*4+0], t4.x, a); a = fmaf(qv[j*4+1], t4.y, a);
                a = fmaf(qv[j*4+2], t4.z, a); a = fmaf(qv[j*4+3], t4.w, a);
            }
            rw[kc] = a;
        }
        #pragma unroll
        for (int kr = 0; kr < 12; ++kr) {
            const float* rp = relh + (kr - qr + 11) * 16;
            float a = 0.f;
            #pragma unroll
            for (int j = 0; j < 4; ++j) {
                float4 t4 = *(const float4*)(rp + j * 4);
                a = fmaf(qv[j*4+0], t4.x, a); a = fmaf(qv[j*4+1], t4.y, a);
                a = fmaf(qv[j*4+2], t4.z, a); a = fmaf(qv[j*4+3], t4.w, a);
            }
            rh[kr] = a;
        }
        unsigned rr[16];
        #pragma unroll
        for (int j = 0; j < 6; ++j) rr[j]     = h2u(pkrtz(L2E * rw[2*j], L2E * rw[2*j+1]));
        #pragma unroll
        for (int j = 0; j < 6; ++j) rr[6 + j] = h2u(pkrtz(L2E * rh[2*j], L2E * rh[2*j+1]));
        rr[12] = rr[13] = rr[14] = rr[15] = 0u;
        uint4* dst = (uint4*)(Rel + h * 4096 + l * 64);
        dst[0] = make_uint4(rr[0], rr[1], rr[2],  rr[3]);
        dst[1] = make_uint4(rr[4], rr[5], rr[6],  rr[7]);
        dst[2] = make_uint4(rr[8], rr[9], rr[10], rr[11]);
        dst[3] = make_uint4(rr[12], rr[13], rr[14], rr[15]);
    }
    __syncthreads();

    // ---- B-fragments (persist): Q scaled by 0.25*log2e, rel step1/step2 ----
    f16x4 qb[4], rb1[4], rb2[4];
    {
        const h2_t qsc = { (_Float16)(0.25f * L2E), (_Float16)(0.25f * L2E) };
        #pragma unroll
        for (int tn = 0; tn < 4; ++tn) {
            int q = tn * 16 + (l & 15);
            int qr = q >> 3, qc = q & 7;
            uint2 raw = *(const uint2*)(qs + ((size_t)(b * HWc) + (y0 + qr) * Ww + (x0 + qc)) * 64 + h * 16 + dgrp * 4);
            h2_t lo = u2h(raw.x) * qsc, hi = u2h(raw.y) * qsc;
            u32x2 packed = { h2u(lo), h2u(hi) };
            qb[tn] = __builtin_bit_cast(f16x4, packed);
            const unsigned char* rbase = Rel + h * 4096 + q * 64 + dgrp * 8;
            rb1[tn] = *(const f16x4*)rbase;
            rb2[tn] = *(const f16x4*)(rbase + 32);
        }
    }

    // ---- main loop over 9 key tiles, 2-deep ka/va prefetch ----
    f32x4 Oacc[4];
    float lsum[4];
    #pragma unroll
    for (int tn = 0; tn < 4; ++tn) { Oacc[tn] = (f32x4){0.f,0.f,0.f,0.f}; lsum[tn] = 0.f; }
    const f32x4 zf = {0.f, 0.f, 0.f, 0.f};
    const float SH = 3.0f * L2E;

    f16x4 kaA = *(const f16x4*)(Kl + h * 4608 + (l & 15) * 32 + dgrp * 8);
    f16x4 vaA = *(const f16x4*)(Vt + h * 4736 + (l & 15) * 296 + (dgrp * 4) * 2);

    #pragma unroll 1
    for (int tm = 0; tm < 9; ++tm) {
        int tmn = (tm + 1 < 9) ? tm + 1 : 0;
        f16x4 kaB = *(const f16x4*)(Kl + h * 4608 + (tmn * 16 + (l & 15)) * 32 + dgrp * 8);
        f16x4 vaB = *(const f16x4*)(Vt + h * 4736 + (l & 15) * 296 + (tmn * 16 + dgrp * 4) * 2);

        int key = tm * 16 + (l & 15);
        int kr = (key * 2731) >> 15;
        int kc = key - kr * 12;
        f16x4 oh1, oh2;
        #pragma unroll
        for (int i = 0; i < 4; ++i) {
            int a1 = 4 * dgrp + i;
            bool v1 = (a1 < 12) ? (kc == a1) : (kr == a1 - 12);
            oh1[i] = v1 ? (_Float16)1.0f : (_Float16)0.0f;
            int a2 = 16 + 4 * dgrp + i;
            bool v2 = (a2 < 24) && (kr == a2 - 12);
            oh2[i] = v2 ? (_Float16)1.0f : (_Float16)0.0f;
        }

        #pragma unroll
        for (int tn = 0; tn < 4; ++tn) {
            f32x4 s = __builtin_amdgcn_mfma_f32_16x16x16f16(kaA, qb[tn],  zf, 0, 0, 0);
            s       = __builtin_amdgcn_mfma_f32_16x16x16f16(oh1, rb1[tn], s,  0, 0, 0);
            s       = __builtin_amdgcn_mfma_f32_16x16x16f16(oh2, rb2[tn], s,  0, 0, 0);
            float e0 = exp2f(s[0] - SH);
            float e1 = exp2f(s[1] - SH);
            float e2 = exp2f(s[2] - SH);
            float e3 = exp2f(s[3] - SH);
            lsum[tn] += (e0 + e1) + (e2 + e3);
            u32x2 pp = { h2u(pkrtz(e0, e1)), h2u(pkrtz(e2, e3)) };
            f16x4 pb = __builtin_bit_cast(f16x4, pp);
            Oacc[tn] = __builtin_amdgcn_mfma_f32_16x16x16f16(vaA, pb, Oacc[tn], 0, 0, 0);
        }
        kaA = kaB; vaA = vaB;
    }

    // ---- normalize + write f16 to mldsh (aliases Kl) ----
    __syncthreads();
    #pragma unroll
    for (int tn = 0; tn < 4; ++tn) {
        float s = lsum[tn];
        s += __shfl_xor(s, 16);
        s += __shfl_xor(s, 32);
        float inv = 1.f / s;
        int q = tn * 16 + (l & 15);
        u32x2 w2 = { h2u(pkrtz(Oacc[tn][0] * inv, Oacc[tn][1] * inv)),
                     h2u(pkrtz(Oacc[tn][2] * inv, Oacc[tn][3] * inv)) };
        *(u32x2*)&mldsh[q][h * 16 + dgrp * 4] = w2;
    }
    __syncthreads();

    // ---- fused out-conv via MFMA: D[48oc x 64px] = w_out(f16) . mldsh ----
    {
        int tn2 = h;
        int pxl = tn2 * 16 + (l & 15);
        f16x4 bf[4];
        #pragma unroll
        for (int ks = 0; ks < 4; ++ks)
            bf[ks] = *(const f16x4*)&mldsh[pxl][ks * 16 + dgrp * 4];

        int gy = y0 + (pxl >> 3), gx = x0 + (pxl & 7);
        #pragma unroll
        for (int ot = 0; ot < 3; ++ot) {
            float4 bi = *(const float4*)(b_out + ot * 16 + dgrp * 4);
            f32x4 Cacc = { bi.x, bi.y, bi.z, bi.w };
            #pragma unroll
            for (int ks = 0; ks < 4; ++ks) {
                float4 wv = *(const float4*)(w_out + (ot * 16 + (l & 15)) * 64 + ks * 16 + dgrp * 4);
                Cacc = __builtin_amdgcn_mfma_f32_16x16x16f16(pk4(wv), bf[ks], Cacc, 0, 0, 0);
            }
            #pragma unroll
            for (int i = 0; i < 4; ++i)
                out[((size_t)(b * 48 + ot * 16 + dgrp * 4 + i)) * HWc + gy * Ww + gx] = Cacc[i];
        }
    }
}

// ---- K5b: easy windows — vs*sa (f16) + MFMA out-conv ----
__global__ __launch_bounds__(256) void k_easy(const float* __restrict__ vsb,
    const float* __restrict__ sab, const int* __restrict__ easyl,
    const float* __restrict__ w_out, const float* __restrict__ b_out,
    float* __restrict__ out)
{
    __shared__ __align__(16) _Float16 mldsh[64][72];   // 9216 B

    int tid = threadIdx.x;
    int blk = blockIdx.x;
    int b = blk / NKc;
    int n = easyl[blk];
    int hy = n / WNc, wx = n % WNc;
    int y0 = hy * 8, x0 = wx * 8;

    {
        int l = tid >> 2, part = tid & 3;
        int gy = y0 + (l >> 3), gx = x0 + (l & 7);
        const float* vp = vsb + ((size_t)(b * HWc) + gy * Ww + gx) * 64 + part * 16;
        float sv = sab[(size_t)b * HWc + gy * Ww + gx];
        #pragma unroll
        for (int j = 0; j < 4; ++j) {
            float4 v4 = *(const float4*)(vp + j * 4);
            u32x2 w2 = { h2u(pkrtz(v4.x * sv, v4.y * sv)),
                         h2u(pkrtz(v4.z * sv, v4.w * sv)) };
            *(u32x2*)&mldsh[l][part * 16 + j * 4] = w2;
        }
    }
    __syncthreads();

    {
        int l = tid & 63;
        int tn2 = __builtin_amdgcn_readfirstlane(tid >> 6);
        int dgrp = l >> 4;
        int pxl = tn2 * 16 + (l & 15);
        f16x4 bf[4];
        #pragma unroll
        for (int ks = 0; ks < 4; ++ks)
            bf[ks] = *(const f16x4*)&mldsh[pxl][ks * 16 + dgrp * 4];

        int gy = y0 + (pxl >> 3), gx = x0 + (pxl & 7);
        #pragma unroll
        for (int ot = 0; ot < 3; ++ot) {
            float4 bi = *(const float4*)(b_out + ot * 16 + dgrp * 4);
            f32x4 Cacc = { bi.x, bi.y, bi.z, bi.w };
            #pragma unroll
            for (int ks = 0; ks < 4; ++ks) {
                float4 wv = *(const float4*)(w_out + (ot * 16 + (l & 15)) * 64 + ks * 16 + dgrp * 4);
                Cacc = __builtin_amdgcn_mfma_f32_16x16x16f16(pk4(wv), bf[ks], Cacc, 0, 0, 0);
            }
            #pragma unroll
            for (int i = 0; i < 4; ++i)
                out[((size_t)(b * 48 + ot * 16 + dgrp * 4 + i)) * HWc + gy * Ww + gx] = Cacc[i];
        }
    }
}

extern "C" void kernel_launch(void* const* d_in, const int* in_sizes, int n_in,
                              void* d_out, int out_size, void* d_ws, size_t ws_size,
                              hipStream_t stream)
{
    const float* x    = (const float*)d_in[0];
    const float* cg   = (const float*)d_in[1];
    const float* wq   = (const float*)d_in[2];
    const float* bq   = (const float*)d_in[3];
    const float* wk   = (const float*)d_in[4];
    const float* bk   = (const float*)d_in[5];
    const float* wv   = (const float*)d_in[6];
    const float* bv   = (const float*)d_in[7];
    const float* w_in = (const float*)d_in[8];
    const float* b_in = (const float*)d_in[9];
    const float* ln_w = (const float*)d_in[10];
    const float* ln_b = (const float*)d_in[11];
    const float* w_sa = (const float*)d_in[12];
    const float* b_sa = (const float*)d_in[13];
    const float* w_m1 = (const float*)d_in[14];
    const float* b_m1 = (const float*)d_in[15];
    const float* w_m2 = (const float*)d_in[16];
    const float* b_m2 = (const float*)d_in[17];
    const float* rel_h= (const float*)d_in[18];
    const float* rel_w= (const float*)d_in[19];
    const float* w_out= (const float*)d_in[20];
    const float* b_out= (const float*)d_in[21];
    float* out = (float*)d_out;

    _Float16* qsh = (_Float16*)d_ws;
    _Float16* ksh = qsh + (size_t)Bc * 64 * HWc;
    float* vs   = (float*)(ksh + (size_t)Bc * 64 * HWc);
    float* sa   = vs + (size_t)Bc * 64 * HWc;
    float* mpix = sa + (size_t)Bc * HWc;
    int*   hardl= (int*)(mpix + (size_t)Bc * HWc);
    int*   easyl= hardl + Bc * NKc;

    k_qkv   <<<1152, 256, 0, stream>>>(x, wq, bq, wk, bk, wv, bv, qsh, ksh, vs);
    k_condsa<<<Bc * Hh, 192, 0, stream>>>(vs, cg, w_in, b_in, ln_w, ln_b, w_sa, b_sa, sa, mpix);
    k_score <<<4, 576, 0, stream>>>(mpix, w_m1, b_m1, w_m2, b_m2, hardl, easyl);
    k_easy  <<<1152, 256, 0, stream>>>(vs, sa, easyl, w_out, b_out, out);
    k_hard  <<<1152, 256, 0, stream>>>(qsh, ksh, vs, hardl, rel_h, rel_w, w_out, b_out, out);
}

// Round 19
// 190.235 us; speedup vs baseline: 1.0952x; 1.0170x over previous
//
#include <hip/hip_runtime.h>
#include <math.h>

#define Hh 192
#define Ww 192
#define HWc 36864
#define Bc 4
#define NWc 576
#define NKc 288
#define WNc 24

typedef _Float16 h2_t __attribute__((ext_vector_type(2)));
typedef _Float16 f16x4 __attribute__((ext_vector_type(4)));
typedef float f32x4 __attribute__((ext_vector_type(4)));
typedef unsigned u32x2 __attribute__((ext_vector_type(2)));
__device__ __forceinline__ h2_t u2h(unsigned u) { return __builtin_bit_cast(h2_t, u); }
__device__ __forceinline__ unsigned h2u(h2_t h) { return __builtin_bit_cast(unsigned, h); }
__device__ __forceinline__ h2_t pkrtz(float a, float b) {
    return __builtin_bit_cast(h2_t, __builtin_amdgcn_cvt_pkrtz(a, b));
}
__device__ __forceinline__ f16x4 pk4(float4 v) {
    u32x2 p = { h2u(pkrtz(v.x, v.y)), h2u(pkrtz(v.z, v.w)) };
    return __builtin_bit_cast(f16x4, p);
}
#define L2E 1.44269504f

// ---- K1: q/k/v 1x1 convs, layout [b][y][x][c] ----
// q,k: f16 MFMA. v: hi/lo-split MFMA (Wh*xh + Wh*xl + Wl*xh) — f32-accurate
// to ~1e-7 rel, 100x under the selection score gap; deletes the VALU v-loop
// and its 1536 broadcast LDS reads per block.
__global__ __launch_bounds__(256, 1) void k_qkv(const float* __restrict__ x,
    const float* __restrict__ wq, const float* __restrict__ bq,
    const float* __restrict__ wk, const float* __restrict__ bk,
    const float* __restrict__ wvw, const float* __restrict__ bv,
    _Float16* __restrict__ q, _Float16* __restrict__ k, float* __restrict__ v)
{
    __shared__ float xs[132][52];

    int tid = threadIdx.x;
    int blk = blockIdx.x;
    int b = blk / 288;
    int g0 = (blk % 288) * 128;
    const float* xb = x + (size_t)b * 48 * HWc + g0;

    #pragma unroll
    for (int it = 0; it < 24; ++it) {
        int i = it * 256 + tid;
        int c = i >> 7, px = i & 127;
        xs[px][c] = xb[(size_t)c * HWc + px];
    }

    int ln = tid & 63, wave = tid >> 6;
    int dgrp = ln >> 4;
    __syncthreads();

    size_t pbase = (size_t)b * HWc + g0;

    // ---- section 1: q/k via MFMA (scoped; regs release before v) ----
    {
        f16x4 Aq[4][3], Ak[4][3];
        #pragma unroll
        for (int ot = 0; ot < 4; ++ot)
            #pragma unroll
            for (int ks = 0; ks < 3; ++ks) {
                int oc = ot * 16 + (ln & 15);
                Aq[ot][ks] = pk4(*(const float4*)(wq + oc * 48 + ks * 16 + dgrp * 4));
                Ak[ot][ks] = pk4(*(const float4*)(wk + oc * 48 + ks * 16 + dgrp * 4));
            }
        float4 bqf[4], bkf[4];
        #pragma unroll
        for (int ot = 0; ot < 4; ++ot) {
            bqf[ot] = *(const float4*)(bq + ot * 16 + dgrp * 4);
            bkf[ot] = *(const float4*)(bk + ot * 16 + dgrp * 4);
        }

        #pragma unroll
        for (int t2 = 0; t2 < 2; ++t2) {
            int tn = wave * 2 + t2;
            int px = tn * 16 + (ln & 15);
            f16x4 Bf[3];
            #pragma unroll
            for (int ks = 0; ks < 3; ++ks)
                Bf[ks] = pk4(*(const float4*)&xs[px][ks * 16 + dgrp * 4]);

            #pragma unroll
            for (int ot = 0; ot < 4; ++ot) {
                f32x4 Dq = { bqf[ot].x, bqf[ot].y, bqf[ot].z, bqf[ot].w };
                f32x4 Dk = { bkf[ot].x, bkf[ot].y, bkf[ot].z, bkf[ot].w };
                #pragma unroll
                for (int ks = 0; ks < 3; ++ks) {
                    Dq = __builtin_amdgcn_mfma_f32_16x16x16f16(Aq[ot][ks], Bf[ks], Dq, 0, 0, 0);
                    Dk = __builtin_amdgcn_mfma_f32_16x16x16f16(Ak[ot][ks], Bf[ks], Dk, 0, 0, 0);
                }
                u32x2 q2 = { h2u(pkrtz(Dq[0], Dq[1])), h2u(pkrtz(Dq[2], Dq[3])) };
                u32x2 k2 = { h2u(pkrtz(Dk[0], Dk[1])), h2u(pkrtz(Dk[2], Dk[3])) };
                size_t off = (pbase + (size_t)px) * 64 + ot * 16 + dgrp * 4;
                *(u32x2*)(q + off) = q2;
                *(u32x2*)(k + off) = k2;
            }
        }
    }

    // ---- section 2: v via hi/lo-split MFMA (scoped) ----
    {
        f16x4 Avh[4][3], Avl[4][3];
        #pragma unroll
        for (int ot = 0; ot < 4; ++ot)
            #pragma unroll
            for (int ks = 0; ks < 3; ++ks) {
                int oc = ot * 16 + (ln & 15);
                float4 w4 = *(const float4*)(wvw + oc * 48 + ks * 16 + dgrp * 4);
                f16x4 wh = pk4(w4);
                float4 wr = make_float4(w4.x - (float)wh[0], w4.y - (float)wh[1],
                                        w4.z - (float)wh[2], w4.w - (float)wh[3]);
                Avh[ot][ks] = wh;
                Avl[ot][ks] = pk4(wr);
            }
        float4 bvf[4];
        #pragma unroll
        for (int ot = 0; ot < 4; ++ot) bvf[ot] = *(const float4*)(bv + ot * 16 + dgrp * 4);

        #pragma unroll
        for (int t2 = 0; t2 < 2; ++t2) {
            int tn = wave * 2 + t2;
            int px = tn * 16 + (ln & 15);
            f16x4 Bh[3], Bl[3];
            #pragma unroll
            for (int ks = 0; ks < 3; ++ks) {
                float4 x4 = *(const float4*)&xs[px][ks * 16 + dgrp * 4];
                f16x4 xh = pk4(x4);
                float4 xr = make_float4(x4.x - (float)xh[0], x4.y - (float)xh[1],
                                        x4.z - (float)xh[2], x4.w - (float)xh[3]);
                Bh[ks] = xh;
                Bl[ks] = pk4(xr);
            }
            #pragma unroll
            for (int ot = 0; ot < 4; ++ot) {
                f32x4 D = { bvf[ot].x, bvf[ot].y, bvf[ot].z, bvf[ot].w };
                #pragma unroll
                for (int ks = 0; ks < 3; ++ks) {
                    D = __builtin_amdgcn_mfma_f32_16x16x16f16(Avh[ot][ks], Bh[ks], D, 0, 0, 0);
                    D = __builtin_amdgcn_mfma_f32_16x16x16f16(Avh[ot][ks], Bl[ks], D, 0, 0, 0);
                    D = __builtin_amdgcn_mfma_f32_16x16x16f16(Avl[ot][ks], Bh[ks], D, 0, 0, 0);
                }
                *(float4*)(v + (pbase + (size_t)px) * 64 + ot * 16 + dgrp * 4) =
                    make_float4(D[0], D[1], D[2], D[3]);
            }
        }
    }
}

// -- K2: FUSED cond conv (68->17) + LayerNorm + leaky + mpix + 3x3 conv + sigmoid --
__global__ __launch_bounds__(192) void k_condsa(const float* __restrict__ vs,
    const float* __restrict__ cg,
    const float* __restrict__ w_in, const float* __restrict__ b_in,
    const float* __restrict__ ln_w, const float* __restrict__ ln_b,
    const float* __restrict__ w_sa, const float* __restrict__ b_sa,
    float* __restrict__ sa, float* __restrict__ mpix)
{
    __shared__ float tl[3][17][194];   // 39.5 KB

    int px = threadIdx.x;              // 0..191
    int blk = blockIdx.x;
    int b = blk / Hh;
    int y = blk % Hh;
    const float step = 2.0f / 7.0f;
    float gx_in = -1.0f + step * (float)(px & 7);

    #pragma unroll 1
    for (int r = 0; r < 3; ++r) {
        int yy = y - 1 + r;
        if ((unsigned)yy >= 192u) continue;
        size_t prem = (size_t)yy * Ww + px;

        float in[68];
        const float* vp = vs + ((size_t)b * HWc + prem) * 64;
        #pragma unroll
        for (int c = 0; c < 64; c += 4) {
            float4 t4 = *(const float4*)(vp + c);
            in[c] = t4.x; in[c+1] = t4.y; in[c+2] = t4.z; in[c+3] = t4.w;
        }
        in[64] = cg[((size_t)b * 2 + 0) * HWc + prem];
        in[65] = cg[((size_t)b * 2 + 1) * HWc + prem];
        in[66] = -1.0f + step * (float)(yy & 7);
        in[67] = gx_in;

        float tv[17];
        float mu = 0.f;
        #pragma unroll
        for (int o = 0; o < 17; ++o) {
            float a = b_in[o];
            const float* wr = w_in + o * 68;
            #pragma unroll
            for (int c = 0; c < 68; ++c) a = fmaf(in[c], wr[c], a);
            tv[o] = a;
            mu += a;
        }
        mu *= (1.f / 17.f);
        float var = 0.f;
        #pragma unroll
        for (int o = 0; o < 17; ++o) { float d = tv[o] - mu; var = fmaf(d, d, var); }
        var *= (1.f / 17.f);
        float rstd = 1.f / sqrtf(var + 1e-6f);

        float msum = 0.f;
        #pragma unroll
        for (int o = 0; o < 17; ++o) {
            float z = (tv[o] - mu) * rstd * ln_w[o] + ln_b[o];
            z = (z >= 0.f) ? z : 0.1f * z;
            tl[r][o][px] = z;
            msum += z;
        }
        if (r == 1) mpix[(size_t)b * HWc + prem] = msum * (1.f / 17.f);
    }
    __syncthreads();

    float a = b_sa[0];
    #pragma unroll 1
    for (int c = 0; c < 17; ++c) {
        const float* wr = w_sa + c * 9;
        #pragma unroll
        for (int ki = 0; ki < 3; ++ki) {
            int yy = y + ki - 1;
            if ((unsigned)yy >= 192u) continue;
            #pragma unroll
            for (int kj = 0; kj < 3; ++kj) {
                int xc = px + kj - 1;
                if ((unsigned)xc >= 192u) continue;
                a = fmaf(tl[ki][c][xc], wr[ki * 3 + kj], a);
            }
        }
    }
    sa[(size_t)b * HWc + (size_t)y * Ww + px] = 1.f / (1.f + expf(-a));
}

// -- K4: window score MLP + stable descending rank -> compacted lists --
__global__ __launch_bounds__(576) void k_score(const float* __restrict__ mpix,
    const float* __restrict__ w_m1, const float* __restrict__ b_m1,
    const float* __restrict__ w_m2, const float* __restrict__ b_m2,
    int* __restrict__ hardl, int* __restrict__ easyl)
{
    __shared__ float sc[NWc];
    int b = blockIdx.x;
    int w = threadIdx.x;
    {
        int hy = w / WNc, wx = w % WNc;
        const float* mp = mpix + (size_t)b * HWc + (hy * 8) * Ww + wx * 8;
        float m[64];
        #pragma unroll
        for (int l = 0; l < 64; ++l) m[l] = mp[(l >> 3) * Ww + (l & 7)];
        float h1[8];
        #pragma unroll
        for (int j = 0; j < 8; ++j) {
            float a = b_m1[j];
            const float* wr = w_m1 + j * 64;
            #pragma unroll
            for (int l = 0; l < 64; ++l) a = fmaf(m[l], wr[l], a);
            h1[j] = (a >= 0.f) ? a : 0.1f * a;
        }
        float l0 = b_m2[0], l1 = b_m2[1];
        #pragma unroll
        for (int j = 0; j < 8; ++j) {
            l0 = fmaf(h1[j], w_m2[j], l0);
            l1 = fmaf(h1[j], w_m2[8 + j], l1);
        }
        float mx = fmaxf(l0, l1);
        float e0 = expf(l0 - mx), e1 = expf(l1 - mx);
        sc[w] = e0 / (e0 + e1);
    }
    __syncthreads();
    float s = sc[w];
    int cnt = 0;
    for (int w2 = 0; w2 < NWc; ++w2) {
        float s2 = sc[w2];
        cnt += ((s2 > s) || (s2 == s && w2 < w)) ? 1 : 0;
    }
    if (cnt < NKc) hardl[b * NKc + cnt] = w;
    else           easyl[b * NKc + (cnt - NKc)] = w;
}

// ---- K5a: hard windows — MFMA flash attention + MFMA out-conv ----
// Rel rows shrunk 64B->48B (+64B zero guard): B-dims 40-47 are multiplied by
// zero A-rows so the overread garbage is harmless; guard stops NaN bits.
// LDS 49728 B <= 53333 -> 3 blocks/CU (was 2).
__global__ __launch_bounds__(256) void k_hard(const _Float16* __restrict__ qs,
    const _Float16* __restrict__ ks, const float* __restrict__ vsb,
    const int* __restrict__ hardl,
    const float* __restrict__ relh, const float* __restrict__ relw,
    const float* __restrict__ w_out, const float* __restrict__ b_out,
    float* __restrict__ out)
{
    __shared__ __align__(16) unsigned char smem[49728];
    unsigned char* Kl  = smem;              // [4][144][16ch f16 =32B], 18432 B
    unsigned char* Vt  = smem + 18432;      // [4][16 d][148 k] f16, 18944 B
    unsigned char* Rel = smem + 37376;      // [4][64 q][48B] + 64B guard, 12352 B
    _Float16 (*mldsh)[72] = (_Float16 (*)[72])smem;  // 9216 B, aliases Kl

    int tid = threadIdx.x;
    int blk = blockIdx.x;
    int b = blk / NKc;
    int n = hardl[blk];
    int hy = n / WNc, wx = n % WNc;
    int y0 = hy * 8, x0 = wx * 8;

    // ---- stage K (f16 copy) and V (f32->f16, d-major, 148-padded), zero OOB ----
    #pragma unroll
    for (int i = 0; i < 9; ++i) {
        int idx = i * 256 + tid;
        int px = idx >> 4, c4 = idx & 15;
        int py = px / 12, pxx = px - py * 12;
        int ky = y0 - 2 + py, kx = x0 - 2 + pxx;
        bool ok = ((unsigned)ky < 192u) && ((unsigned)kx < 192u);
        int kyc = min(max(ky, 0), 191), kxc = min(max(kx, 0), 191);
        size_t poff = ((size_t)(b * HWc) + kyc * Ww + kxc) * 64 + c4 * 4;
        uint2 k2 = *(const uint2*)(ks + poff);
        float4 v4 = *(const float4*)(vsb + poff);
        if (!ok) { k2 = make_uint2(0, 0); v4 = make_float4(0, 0, 0, 0); }
        int hd = c4 >> 2, d0 = (c4 & 3) * 4;
        *(uint2*)(Kl + hd * 4608 + px * 32 + (c4 & 3) * 8) = k2;
        _Float16* vh = (_Float16*)(Vt + hd * 4736);
        vh[(d0 + 0) * 148 + px] = (_Float16)v4.x;
        vh[(d0 + 1) * 148 + px] = (_Float16)v4.y;
        vh[(d0 + 2) * 148 + px] = (_Float16)v4.z;
        vh[(d0 + 3) * 148 + px] = (_Float16)v4.w;
    }
    if (tid < 16) *(unsigned*)(Rel + 12288 + tid * 4) = 0u;   // guard

    int h = __builtin_amdgcn_readfirstlane(tid >> 6);  // head (wave-uniform)
    int l = tid & 63;
    int dgrp = l >> 4;

    // ---- rel tables (log2e-scaled), 48B/q rows ----
    {
        int qr = l >> 3, qc = l & 7;
        const _Float16* qp = qs + ((size_t)(b * HWc) + (y0 + qr) * Ww + (x0 + qc)) * 64 + h * 16;
        uint4 q0 = *(const uint4*)qp;
        uint4 q1 = *(const uint4*)(qp + 8);
        h2_t qhp[8] = { u2h(q0.x), u2h(q0.y), u2h(q0.z), u2h(q0.w),
                        u2h(q1.x), u2h(q1.y), u2h(q1.z), u2h(q1.w) };
        float qv[16];
        #pragma unroll
        for (int j = 0; j < 8; ++j) { qv[2*j] = (float)qhp[j].x; qv[2*j+1] = (float)qhp[j].y; }

        float rw[12], rh[12];
        #pragma unroll
        for (int kc = 0; kc < 12; ++kc) {
            const float* rp = relw + (kc - qc + 11) * 16;
            float a = 0.f;
            #pragma unroll
            for (int j = 0; j < 4; ++j) {
                float4 t4 = *(const float4*)(rp + j * 4);
                a = fmaf(qv[j*4+0], t4.x, a); a = fmaf(qv[j*4+1], t4.y, a);
                a = fmaf(qv[j*4+2], t4.z, a); a = fmaf(qv[j*4+3], t4.w, a);
            }
            rw[kc] = a;
        }
        #pragma unroll
        for (int kr = 0; kr < 12; ++kr) {
            const float* rp = relh + (kr - qr + 11) * 16;
            float a = 0.f;
            #pragma unroll
            for (int j = 0; j < 4; ++j) {
                float4 t4 = *(const float4*)(rp + j * 4);
                a = fmaf(qv[j*4+0], t4.x, a); a = fmaf(qv[j*4+1], t4.y, a);
                a = fmaf(qv[j*4+2], t4.z, a); a = fmaf(qv[j*4+3], t4.w, a);
            }
            rh[kr] = a;
        }
        unsigned rr[12];
        #pragma unroll
        for (int j = 0; j < 6; ++j) rr[j]     = h2u(pkrtz(L2E * rw[2*j], L2E * rw[2*j+1]));
        #pragma unroll
        for (int j = 0; j < 6; ++j) rr[6 + j] = h2u(pkrtz(L2E * rh[2*j], L2E * rh[2*j+1]));
        uint4* dst = (uint4*)(Rel + h * 3072 + l * 48);
        dst[0] = make_uint4(rr[0], rr[1], rr[2],  rr[3]);
        dst[1] = make_uint4(rr[4], rr[5], rr[6],  rr[7]);
        dst[2] = make_uint4(rr[8], rr[9], rr[10], rr[11]);
    }
    __syncthreads();

    // ---- B-fragments (persist): Q scaled by 0.25*log2e, rel step1/step2 ----
    f16x4 qb[4], rb1[4], rb2[4];
    {
        const h2_t qsc = { (_Float16)(0.25f * L2E), (_Float16)(0.25f * L2E) };
        #pragma unroll
        for (int tn = 0; tn < 4; ++tn) {
            int q = tn * 16 + (l & 15);
            int qr = q >> 3, qc = q & 7;
            uint2 raw = *(const uint2*)(qs + ((size_t)(b * HWc) + (y0 + qr) * Ww + (x0 + qc)) * 64 + h * 16 + dgrp * 4);
            h2_t lo = u2h(raw.x) * qsc, hi = u2h(raw.y) * qsc;
            u32x2 packed = { h2u(lo), h2u(hi) };
            qb[tn] = __builtin_bit_cast(f16x4, packed);
            const unsigned char* rbase = Rel + h * 3072 + q * 48 + dgrp * 8;
            rb1[tn] = *(const f16x4*)rbase;
            rb2[tn] = *(const f16x4*)(rbase + 32);
        }
    }

    // ---- main loop over 9 key tiles, 2-deep ka/va prefetch ----
    f32x4 Oacc[4];
    float lsum[4];
    #pragma unroll
    for (int tn = 0; tn < 4; ++tn) { Oacc[tn] = (f32x4){0.f,0.f,0.f,0.f}; lsum[tn] = 0.f; }
    const f32x4 zf = {0.f, 0.f, 0.f, 0.f};
    const float SH = 3.0f * L2E;

    f16x4 kaA = *(const f16x4*)(Kl + h * 4608 + (l & 15) * 32 + dgrp * 8);
    f16x4 vaA = *(const f16x4*)(Vt + h * 4736 + (l & 15) * 296 + (dgrp * 4) * 2);

    #pragma unroll 1
    for (int tm = 0; tm < 9; ++tm) {
        int tmn = (tm + 1 < 9) ? tm + 1 : 0;
        f16x4 kaB = *(const f16x4*)(Kl + h * 4608 + (tmn * 16 + (l & 15)) * 32 + dgrp * 8);
        f16x4 vaB = *(const f16x4*)(Vt + h * 4736 + (l & 15) * 296 + (tmn * 16 + dgrp * 4) * 2);

        int key = tm * 16 + (l & 15);
        int kr = (key * 2731) >> 15;
        int kc = key - kr * 12;
        f16x4 oh1, oh2;
        #pragma unroll
        for (int i = 0; i < 4; ++i) {
            int a1 = 4 * dgrp + i;
            bool v1 = (a1 < 12) ? (kc == a1) : (kr == a1 - 12);
            oh1[i] = v1 ? (_Float16)1.0f : (_Float16)0.0f;
            int a2 = 16 + 4 * dgrp + i;
            bool v2 = (a2 < 24) && (kr == a2 - 12);
            oh2[i] = v2 ? (_Float16)1.0f : (_Float16)0.0f;
        }

        #pragma unroll
        for (int tn = 0; tn < 4; ++tn) {
            f32x4 s = __builtin_amdgcn_mfma_f32_16x16x16f16(kaA, qb[tn],  zf, 0, 0, 0);
            s       = __builtin_amdgcn_mfma_f32_16x16x16f16(oh1, rb1[tn], s,  0, 0, 0);
            s       = __builtin_amdgcn_mfma_f32_16x16x16f16(oh2, rb2[tn], s,  0, 0, 0);
            float e0 = exp2f(s[0] - SH);
            float e1 = exp2f(s[1] - SH);
            float e2 = exp2f(s[2] - SH);
            float e3 = exp2f(s[3] - SH);
            lsum[tn] += (e0 + e1) + (e2 + e3);
            u32x2 pp = { h2u(pkrtz(e0, e1)), h2u(pkrtz(e2, e3)) };
            f16x4 pb = __builtin_bit_cast(f16x4, pp);
            Oacc[tn] = __builtin_amdgcn_mfma_f32_16x16x16f16(vaA, pb, Oacc[tn], 0, 0, 0);
        }
        kaA = kaB; vaA = vaB;
    }

    // ---- normalize + write f16 to mldsh (aliases Kl) ----
    __syncthreads();
    #pragma unroll
    for (int tn = 0; tn < 4; ++tn) {
        float s = lsum[tn];
        s += __shfl_xor(s, 16);
        s += __shfl_xor(s, 32);
        float inv = 1.f / s;
        int q = tn * 16 + (l & 15);
        u32x2 w2 = { h2u(pkrtz(Oacc[tn][0] * inv, Oacc[tn][1] * inv)),
                     h2u(pkrtz(Oacc[tn][2] * inv, Oacc[tn][3] * inv)) };
        *(u32x2*)&mldsh[q][h * 16 + dgrp * 4] = w2;
    }
    __syncthreads();

    // ---- fused out-conv via MFMA: D[48oc x 64px] = w_out(f16) . mldsh ----
    {
        int tn2 = h;
        int pxl = tn2 * 16 + (l & 15);
        f16x4 bf[4];
        #pragma unroll
        for (int ks = 0; ks < 4; ++ks)
            bf[ks] = *(const f16x4*)&mldsh[pxl][ks * 16 + dgrp * 4];

        int gy = y0 + (pxl >> 3), gx = x0 + (pxl & 7);
        #pragma unroll
        for (int ot = 0; ot < 3; ++ot) {
            float4 bi = *(const float4*)(b_out + ot * 16 + dgrp * 4);
            f32x4 Cacc = { bi.x, bi.y, bi.z, bi.w };
            #pragma unroll
            for (int ks = 0; ks < 4; ++ks) {
                float4 wv = *(const float4*)(w_out + (ot * 16 + (l & 15)) * 64 + ks * 16 + dgrp * 4);
                Cacc = __builtin_amdgcn_mfma_f32_16x16x16f16(pk4(wv), bf[ks], Cacc, 0, 0, 0);
            }
            #pragma unroll
            for (int i = 0; i < 4; ++i)
                out[((size_t)(b * 48 + ot * 16 + dgrp * 4 + i)) * HWc + gy * Ww + gx] = Cacc[i];
        }
    }
}

// ---- K5b: easy windows — vs*sa (f16) + MFMA out-conv ----
__global__ __launch_bounds__(256) void k_easy(const float* __restrict__ vsb,
    const float* __restrict__ sab, const int* __restrict__ easyl,
    const float* __restrict__ w_out, const float* __restrict__ b_out,
    float* __restrict__ out)
{
    __shared__ __align__(16) _Float16 mldsh[64][72];   // 9216 B

    int tid = threadIdx.x;
    int blk = blockIdx.x;
    int b = blk / NKc;
    int n = easyl[blk];
    int hy = n / WNc, wx = n % WNc;
    int y0 = hy * 8, x0 = wx * 8;

    {
        int l = tid >> 2, part = tid & 3;
        int gy = y0 + (l >> 3), gx = x0 + (l & 7);
        const float* vp = vsb + ((size_t)(b * HWc) + gy * Ww + gx) * 64 + part * 16;
        float sv = sab[(size_t)b * HWc + gy * Ww + gx];
        #pragma unroll
        for (int j = 0; j < 4; ++j) {
            float4 v4 = *(const float4*)(vp + j * 4);
            u32x2 w2 = { h2u(pkrtz(v4.x * sv, v4.y * sv)),
                         h2u(pkrtz(v4.z * sv, v4.w * sv)) };
            *(u32x2*)&mldsh[l][part * 16 + j * 4] = w2;
        }
    }
    __syncthreads();

    {
        int l = tid & 63;
        int tn2 = __builtin_amdgcn_readfirstlane(tid >> 6);
        int dgrp = l >> 4;
        int pxl = tn2 * 16 + (l & 15);
        f16x4 bf[4];
        #pragma unroll
        for (int ks = 0; ks < 4; ++ks)
            bf[ks] = *(const f16x4*)&mldsh[pxl][ks * 16 + dgrp * 4];

        int gy = y0 + (pxl >> 3), gx = x0 + (pxl & 7);
        #pragma unroll
        for (int ot = 0; ot < 3; ++ot) {
            float4 bi = *(const float4*)(b_out + ot * 16 + dgrp * 4);
            f32x4 Cacc = { bi.x, bi.y, bi.z, bi.w };
            #pragma unroll
            for (int ks = 0; ks < 4; ++ks) {
                float4 wv = *(const float4*)(w_out + (ot * 16 + (l & 15)) * 64 + ks * 16 + dgrp * 4);
                Cacc = __builtin_amdgcn_mfma_f32_16x16x16f16(pk4(wv), bf[ks], Cacc, 0, 0, 0);
            }
            #pragma unroll
            for (int i = 0; i < 4; ++i)
                out[((size_t)(b * 48 + ot * 16 + dgrp * 4 + i)) * HWc + gy * Ww + gx] = Cacc[i];
        }
    }
}

extern "C" void kernel_launch(void* const* d_in, const int* in_sizes, int n_in,
                              void* d_out, int out_size, void* d_ws, size_t ws_size,
                              hipStream_t stream)
{
    const float* x    = (const float*)d_in[0];
    const float* cg   = (const float*)d_in[1];
    const float* wq   = (const float*)d_in[2];
    const float* bq   = (const float*)d_in[3];
    const float* wk   = (const float*)d_in[4];
    const float* bk   = (const float*)d_in[5];
    const float* wv   = (const float*)d_in[6];
    const float* bv   = (const float*)d_in[7];
    const float* w_in = (const float*)d_in[8];
    const float* b_in = (const float*)d_in[9];
    const float* ln_w = (const float*)d_in[10];
    const float* ln_b = (const float*)d_in[11];
    const float* w_sa = (const float*)d_in[12];
    const float* b_sa = (const float*)d_in[13];
    const float* w_m1 = (const float*)d_in[14];
    const float* b_m1 = (const float*)d_in[15];
    const float* w_m2 = (const float*)d_in[16];
    const float* b_m2 = (const float*)d_in[17];
    const float* rel_h= (const float*)d_in[18];
    const float* rel_w= (const float*)d_in[19];
    const float* w_out= (const float*)d_in[20];
    const float* b_out= (const float*)d_in[21];
    float* out = (float*)d_out;

    _Float16* qsh = (_Float16*)d_ws;
    _Float16* ksh = qsh + (size_t)Bc * 64 * HWc;
    float* vs   = (float*)(ksh + (size_t)Bc * 64 * HWc);
    float* sa   = vs + (size_t)Bc * 64 * HWc;
    float* mpix = sa + (size_t)Bc * HWc;
    int*   hardl= (int*)(mpix + (size_t)Bc * HWc);
    int*   easyl= hardl + Bc * NKc;

    k_qkv   <<<1152, 256, 0, stream>>>(x, wq, bq, wk, bk, wv, bv, qsh, ksh, vs);
    k_condsa<<<Bc * Hh, 192, 0, stream>>>(vs, cg, w_in, b_in, ln_w, ln_b, w_sa, b_sa, sa, mpix);
    k_score <<<4, 576, 0, stream>>>(mpix, w_m1, b_m1, w_m2, b_m2, hardl, easyl);
    k_easy  <<<1152, 256, 0, stream>>>(vs, sa, easyl, w_out, b_out, out);
    k_hard  <<<1152, 256, 0, stream>>>(qsh, ksh, vs, hardl, rel_h, rel_w, w_out, b_out, out);
}

// Round 20
// 175.934 us; speedup vs baseline: 1.1843x; 1.0813x over previous
//
#include <hip/hip_runtime.h>
#include <math.h>

#define Hh 192
#define Ww 192
#define HWc 36864
#define Bc 4
#define NWc 576
#define NKc 288
#define WNc 24

typedef _Float16 h2_t __attribute__((ext_vector_type(2)));
typedef _Float16 f16x4 __attribute__((ext_vector_type(4)));
typedef float f32x4 __attribute__((ext_vector_type(4)));
typedef unsigned u32x2 __attribute__((ext_vector_type(2)));
__device__ __forceinline__ h2_t u2h(unsigned u) { return __builtin_bit_cast(h2_t, u); }
__device__ __forceinline__ unsigned h2u(h2_t h) { return __builtin_bit_cast(unsigned, h); }
__device__ __forceinline__ h2_t pkrtz(float a, float b) {
    return __builtin_bit_cast(h2_t, __builtin_amdgcn_cvt_pkrtz(a, b));
}
__device__ __forceinline__ f16x4 pk4(float4 v) {
    u32x2 p = { h2u(pkrtz(v.x, v.y)), h2u(pkrtz(v.z, v.w)) };
    return __builtin_bit_cast(f16x4, p);
}
#define L2E 1.44269504f

// ---- K1: q/k/v 1x1 convs, layout [b][y][x][c] ----
// All stores now go through a padded LDS out-tile so every global store
// instruction writes lane-contiguous 1KB (R19 showed the kernel pinned at
// ~60us with all pipes idle: 8B/128B-stride and 16B/256B-stride stores
// were line-touch-amplified 4-8x through the write path).
__global__ __launch_bounds__(256, 1) void k_qkv(const float* __restrict__ x,
    const float* __restrict__ wq, const float* __restrict__ bq,
    const float* __restrict__ wk, const float* __restrict__ bk,
    const float* __restrict__ wvw, const float* __restrict__ bv,
    _Float16* __restrict__ q, _Float16* __restrict__ k, float* __restrict__ v)
{
    __shared__ float xs[132][52];                       // 27456 B
    __shared__ __align__(16) unsigned char otile[17408]; // [128][68]f16 / [64][68]f32

    int tid = threadIdx.x;
    int blk = blockIdx.x;
    int b = blk / 288;
    int g0 = (blk % 288) * 128;
    const float* xb = x + (size_t)b * 48 * HWc + g0;

    // stage x: float4 loads (24 wave-instrs total vs 96 scalar)
    #pragma unroll
    for (int it = 0; it < 6; ++it) {
        int i = it * 256 + tid;
        int c = i >> 5, p4 = (i & 31) * 4;
        float4 xv = *(const float4*)(xb + (size_t)c * HWc + p4);
        xs[p4 + 0][c] = xv.x; xs[p4 + 1][c] = xv.y;
        xs[p4 + 2][c] = xv.z; xs[p4 + 3][c] = xv.w;
    }

    int ln = tid & 63, wave = tid >> 6;
    int dgrp = ln >> 4;
    __syncthreads();

    size_t pbase = (size_t)b * HWc + g0;

    // ---- q then k: MFMA -> f16 LDS tile [128][68] -> coalesced store ----
    _Float16* qt = (_Float16*)otile;
    #pragma unroll 1
    for (int sel = 0; sel < 2; ++sel) {
        const float* W  = sel ? wk : wq;
        const float* Bi = sel ? bk : bq;
        _Float16* dst   = sel ? k : q;

        f16x4 A[4][3];
        float4 bf[4];
        #pragma unroll
        for (int ot = 0; ot < 4; ++ot) {
            #pragma unroll
            for (int ks = 0; ks < 3; ++ks)
                A[ot][ks] = pk4(*(const float4*)(W + (ot * 16 + (ln & 15)) * 48 + ks * 16 + dgrp * 4));
            bf[ot] = *(const float4*)(Bi + ot * 16 + dgrp * 4);
        }

        #pragma unroll
        for (int t2 = 0; t2 < 2; ++t2) {
            int px = (wave * 2 + t2) * 16 + (ln & 15);
            f16x4 Bf[3];
            #pragma unroll
            for (int ks = 0; ks < 3; ++ks)
                Bf[ks] = pk4(*(const float4*)&xs[px][ks * 16 + dgrp * 4]);
            #pragma unroll
            for (int ot = 0; ot < 4; ++ot) {
                f32x4 D = { bf[ot].x, bf[ot].y, bf[ot].z, bf[ot].w };
                #pragma unroll
                for (int ks = 0; ks < 3; ++ks)
                    D = __builtin_amdgcn_mfma_f32_16x16x16f16(A[ot][ks], Bf[ks], D, 0, 0, 0);
                u32x2 r2 = { h2u(pkrtz(D[0], D[1])), h2u(pkrtz(D[2], D[3])) };
                *(u32x2*)&qt[px * 68 + ot * 16 + dgrp * 4] = r2;
            }
        }
        __syncthreads();
        // coalesced: 128px x 8 segs(16B) = 1024 chunks, 4 iters
        #pragma unroll
        for (int it = 0; it < 4; ++it) {
            int i = it * 256 + tid;
            int px = i >> 3, seg = i & 7;
            uint4 val = *(const uint4*)&qt[px * 68 + seg * 8];
            *(uint4*)(dst + (pbase + (size_t)px) * 64 + seg * 8) = val;
        }
        __syncthreads();
    }

    // ---- v: hi/lo-split MFMA -> f32 LDS tile [64][68] -> coalesced, 2 passes ----
    {
        f16x4 Avh[4][3], Avl[4][3];
        #pragma unroll
        for (int ot = 0; ot < 4; ++ot)
            #pragma unroll
            for (int ks = 0; ks < 3; ++ks) {
                float4 w4 = *(const float4*)(wvw + (ot * 16 + (ln & 15)) * 48 + ks * 16 + dgrp * 4);
                f16x4 wh = pk4(w4);
                float4 wr = make_float4(w4.x - (float)wh[0], w4.y - (float)wh[1],
                                        w4.z - (float)wh[2], w4.w - (float)wh[3]);
                Avh[ot][ks] = wh;
                Avl[ot][ks] = pk4(wr);
            }
        float4 bvf[4];
        #pragma unroll
        for (int ot = 0; ot < 4; ++ot) bvf[ot] = *(const float4*)(bv + ot * 16 + dgrp * 4);

        float* vt = (float*)otile;
        #pragma unroll 1
        for (int p = 0; p < 2; ++p) {
            int px = (p * 4 + wave) * 16 + (ln & 15);
            f16x4 Bh[3], Bl[3];
            #pragma unroll
            for (int ks = 0; ks < 3; ++ks) {
                float4 x4 = *(const float4*)&xs[px][ks * 16 + dgrp * 4];
                f16x4 xh = pk4(x4);
                float4 xr = make_float4(x4.x - (float)xh[0], x4.y - (float)xh[1],
                                        x4.z - (float)xh[2], x4.w - (float)xh[3]);
                Bh[ks] = xh;
                Bl[ks] = pk4(xr);
            }
            #pragma unroll
            for (int ot = 0; ot < 4; ++ot) {
                f32x4 D = { bvf[ot].x, bvf[ot].y, bvf[ot].z, bvf[ot].w };
                #pragma unroll
                for (int ks = 0; ks < 3; ++ks) {
                    D = __builtin_amdgcn_mfma_f32_16x16x16f16(Avh[ot][ks], Bh[ks], D, 0, 0, 0);
                    D = __builtin_amdgcn_mfma_f32_16x16x16f16(Avh[ot][ks], Bl[ks], D, 0, 0, 0);
                    D = __builtin_amdgcn_mfma_f32_16x16x16f16(Avl[ot][ks], Bh[ks], D, 0, 0, 0);
                }
                *(f32x4*)&vt[(px - p * 64) * 68 + ot * 16 + dgrp * 4] = D;
            }
            __syncthreads();
            // coalesced: 64px x 16 segs(16B) = 1024 chunks, 4 iters
            #pragma unroll
            for (int it = 0; it < 4; ++it) {
                int i = it * 256 + tid;
                int px2 = i >> 4, seg = i & 15;
                float4 val = *(const float4*)&vt[px2 * 68 + seg * 4];
                *(float4*)(v + (pbase + (size_t)(p * 64 + px2)) * 64 + seg * 4) = val;
            }
            __syncthreads();
        }
    }
}

// -- K2: FUSED cond conv (68->17) + LayerNorm + leaky + mpix + 3x3 conv + sigmoid --
__global__ __launch_bounds__(192) void k_condsa(const float* __restrict__ vs,
    const float* __restrict__ cg,
    const float* __restrict__ w_in, const float* __restrict__ b_in,
    const float* __restrict__ ln_w, const float* __restrict__ ln_b,
    const float* __restrict__ w_sa, const float* __restrict__ b_sa,
    float* __restrict__ sa, float* __restrict__ mpix)
{
    __shared__ float tl[3][17][194];   // 39.5 KB

    int px = threadIdx.x;              // 0..191
    int blk = blockIdx.x;
    int b = blk / Hh;
    int y = blk % Hh;
    const float step = 2.0f / 7.0f;
    float gx_in = -1.0f + step * (float)(px & 7);

    #pragma unroll 1
    for (int r = 0; r < 3; ++r) {
        int yy = y - 1 + r;
        if ((unsigned)yy >= 192u) continue;
        size_t prem = (size_t)yy * Ww + px;

        float in[68];
        const float* vp = vs + ((size_t)b * HWc + prem) * 64;
        #pragma unroll
        for (int c = 0; c < 64; c += 4) {
            float4 t4 = *(const float4*)(vp + c);
            in[c] = t4.x; in[c+1] = t4.y; in[c+2] = t4.z; in[c+3] = t4.w;
        }
        in[64] = cg[((size_t)b * 2 + 0) * HWc + prem];
        in[65] = cg[((size_t)b * 2 + 1) * HWc + prem];
        in[66] = -1.0f + step * (float)(yy & 7);
        in[67] = gx_in;

        float tv[17];
        float mu = 0.f;
        #pragma unroll
        for (int o = 0; o < 17; ++o) {
            float a = b_in[o];
            const float* wr = w_in + o * 68;
            #pragma unroll
            for (int c = 0; c < 68; ++c) a = fmaf(in[c], wr[c], a);
            tv[o] = a;
            mu += a;
        }
        mu *= (1.f / 17.f);
        float var = 0.f;
        #pragma unroll
        for (int o = 0; o < 17; ++o) { float d = tv[o] - mu; var = fmaf(d, d, var); }
        var *= (1.f / 17.f);
        float rstd = 1.f / sqrtf(var + 1e-6f);

        float msum = 0.f;
        #pragma unroll
        for (int o = 0; o < 17; ++o) {
            float z = (tv[o] - mu) * rstd * ln_w[o] + ln_b[o];
            z = (z >= 0.f) ? z : 0.1f * z;
            tl[r][o][px] = z;
            msum += z;
        }
        if (r == 1) mpix[(size_t)b * HWc + prem] = msum * (1.f / 17.f);
    }
    __syncthreads();

    float a = b_sa[0];
    #pragma unroll 1
    for (int c = 0; c < 17; ++c) {
        const float* wr = w_sa + c * 9;
        #pragma unroll
        for (int ki = 0; ki < 3; ++ki) {
            int yy = y + ki - 1;
            if ((unsigned)yy >= 192u) continue;
            #pragma unroll
            for (int kj = 0; kj < 3; ++kj) {
                int xc = px + kj - 1;
                if ((unsigned)xc >= 192u) continue;
                a = fmaf(tl[ki][c][xc], wr[ki * 3 + kj], a);
            }
        }
    }
    sa[(size_t)b * HWc + (size_t)y * Ww + px] = 1.f / (1.f + expf(-a));
}

// -- K4: window score MLP + stable descending rank -> compacted lists --
__global__ __launch_bounds__(576) void k_score(const float* __restrict__ mpix,
    const float* __restrict__ w_m1, const float* __restrict__ b_m1,
    const float* __restrict__ w_m2, const float* __restrict__ b_m2,
    int* __restrict__ hardl, int* __restrict__ easyl)
{
    __shared__ float sc[NWc];
    int b = blockIdx.x;
    int w = threadIdx.x;
    {
        int hy = w / WNc, wx = w % WNc;
        const float* mp = mpix + (size_t)b * HWc + (hy * 8) * Ww + wx * 8;
        float m[64];
        #pragma unroll
        for (int l = 0; l < 64; ++l) m[l] = mp[(l >> 3) * Ww + (l & 7)];
        float h1[8];
        #pragma unroll
        for (int j = 0; j < 8; ++j) {
            float a = b_m1[j];
            const float* wr = w_m1 + j * 64;
            #pragma unroll
            for (int l = 0; l < 64; ++l) a = fmaf(m[l], wr[l], a);
            h1[j] = (a >= 0.f) ? a : 0.1f * a;
        }
        float l0 = b_m2[0], l1 = b_m2[1];
        #pragma unroll
        for (int j = 0; j < 8; ++j) {
            l0 = fmaf(h1[j], w_m2[j], l0);
            l1 = fmaf(h1[j], w_m2[8 + j], l1);
        }
        float mx = fmaxf(l0, l1);
        float e0 = expf(l0 - mx), e1 = expf(l1 - mx);
        sc[w] = e0 / (e0 + e1);
    }
    __syncthreads();
    float s = sc[w];
    int cnt = 0;
    for (int w2 = 0; w2 < NWc; ++w2) {
        float s2 = sc[w2];
        cnt += ((s2 > s) || (s2 == s && w2 < w)) ? 1 : 0;
    }
    if (cnt < NKc) hardl[b * NKc + cnt] = w;
    else           easyl[b * NKc + (cnt - NKc)] = w;
}

// ---- K5a: hard windows — MFMA flash attention + MFMA out-conv ----
__global__ __launch_bounds__(256) void k_hard(const _Float16* __restrict__ qs,
    const _Float16* __restrict__ ks, const float* __restrict__ vsb,
    const int* __restrict__ hardl,
    const float* __restrict__ relh, const float* __restrict__ relw,
    const float* __restrict__ w_out, const float* __restrict__ b_out,
    float* __restrict__ out)
{
    __shared__ __align__(16) unsigned char smem[49728];
    unsigned char* Kl  = smem;              // [4][144][16ch f16 =32B], 18432 B
    unsigned char* Vt  = smem + 18432;      // [4][16 d][148 k] f16, 18944 B
    unsigned char* Rel = smem + 37376;      // [4][64 q][48B] + 64B guard, 12352 B
    _Float16 (*mldsh)[72] = (_Float16 (*)[72])smem;  // 9216 B, aliases Kl

    int tid = threadIdx.x;
    int blk = blockIdx.x;
    int b = blk / NKc;
    int n = hardl[blk];
    int hy = n / WNc, wx = n % WNc;
    int y0 = hy * 8, x0 = wx * 8;

    // ---- stage K (f16 copy) and V (f32->f16, d-major, 148-padded), zero OOB ----
    #pragma unroll
    for (int i = 0; i < 9; ++i) {
        int idx = i * 256 + tid;
        int px = idx >> 4, c4 = idx & 15;
        int py = px / 12, pxx = px - py * 12;
        int ky = y0 - 2 + py, kx = x0 - 2 + pxx;
        bool ok = ((unsigned)ky < 192u) && ((unsigned)kx < 192u);
        int kyc = min(max(ky, 0), 191), kxc = min(max(kx, 0), 191);
        size_t poff = ((size_t)(b * HWc) + kyc * Ww + kxc) * 64 + c4 * 4;
        uint2 k2 = *(const uint2*)(ks + poff);
        float4 v4 = *(const float4*)(vsb + poff);
        if (!ok) { k2 = make_uint2(0, 0); v4 = make_float4(0, 0, 0, 0); }
        int hd = c4 >> 2, d0 = (c4 & 3) * 4;
        *(uint2*)(Kl + hd * 4608 + px * 32 + (c4 & 3) * 8) = k2;
        _Float16* vh = (_Float16*)(Vt + hd * 4736);
        vh[(d0 + 0) * 148 + px] = (_Float16)v4.x;
        vh[(d0 + 1) * 148 + px] = (_Float16)v4.y;
        vh[(d0 + 2) * 148 + px] = (_Float16)v4.z;
        vh[(d0 + 3) * 148 + px] = (_Float16)v4.w;
    }
    if (tid < 16) *(unsigned*)(Rel + 12288 + tid * 4) = 0u;   // guard

    int h = __builtin_amdgcn_readfirstlane(tid >> 6);  // head (wave-uniform)
    int l = tid & 63;
    int dgrp = l >> 4;

    // ---- rel tables (log2e-scaled), 48B/q rows ----
    {
        int qr = l >> 3, qc = l & 7;
        const _Float16* qp = qs + ((size_t)(b * HWc) + (y0 + qr) * Ww + (x0 + qc)) * 64 + h * 16;
        uint4 q0 = *(const uint4*)qp;
        uint4 q1 = *(const uint4*)(qp + 8);
        h2_t qhp[8] = { u2h(q0.x), u2h(q0.y), u2h(q0.z), u2h(q0.w),
                        u2h(q1.x), u2h(q1.y), u2h(q1.z), u2h(q1.w) };
        float qv[16];
        #pragma unroll
        for (int j = 0; j < 8; ++j) { qv[2*j] = (float)qhp[j].x; qv[2*j+1] = (float)qhp[j].y; }

        float rw[12], rh[12];
        #pragma unroll
        for (int kc = 0; kc < 12; ++kc) {
            const float* rp = relw + (kc - qc + 11) * 16;
            float a = 0.f;
            #pragma unroll
            for (int j = 0; j < 4; ++j) {
                float4 t4 = *(const float4*)(rp + j * 4);
                a = fmaf(qv[j*4+0], t4.x, a); a = fmaf(qv[j*4+1], t4.y, a);
                a = fmaf(qv[j*4+2], t4.z, a); a = fmaf(qv[j*4+3], t4.w, a);
            }
            rw[kc] = a;
        }
        #pragma unroll
        for (int kr = 0; kr < 12; ++kr) {
            const float* rp = relh + (kr - qr + 11) * 16;
            float a = 0.f;
            #pragma unroll
            for (int j = 0; j < 4; ++j) {
                float4 t4 = *(const float4*)(rp + j * 4);
                a = fmaf(qv[j*4+0], t4.x, a); a = fmaf(qv[j*4+1], t4.y, a);
                a = fmaf(qv[j*4+2], t4.z, a); a = fmaf(qv[j*4+3], t4.w, a);
            }
            rh[kr] = a;
        }
        unsigned rr[12];
        #pragma unroll
        for (int j = 0; j < 6; ++j) rr[j]     = h2u(pkrtz(L2E * rw[2*j], L2E * rw[2*j+1]));
        #pragma unroll
        for (int j = 0; j < 6; ++j) rr[6 + j] = h2u(pkrtz(L2E * rh[2*j], L2E * rh[2*j+1]));
        uint4* dst = (uint4*)(Rel + h * 3072 + l * 48);
        dst[0] = make_uint4(rr[0], rr[1], rr[2],  rr[3]);
        dst[1] = make_uint4(rr[4], rr[5], rr[6],  rr[7]);
        dst[2] = make_uint4(rr[8], rr[9], rr[10], rr[11]);
    }
    __syncthreads();

    // ---- B-fragments (persist): Q scaled by 0.25*log2e, rel step1/step2 ----
    f16x4 qb[4], rb1[4], rb2[4];
    {
        const h2_t qsc = { (_Float16)(0.25f * L2E), (_Float16)(0.25f * L2E) };
        #pragma unroll
        for (int tn = 0; tn < 4; ++tn) {
            int q = tn * 16 + (l & 15);
            int qr = q >> 3, qc = q & 7;
            uint2 raw = *(const uint2*)(qs + ((size_t)(b * HWc) + (y0 + qr) * Ww + (x0 + qc)) * 64 + h * 16 + dgrp * 4);
            h2_t lo = u2h(raw.x) * qsc, hi = u2h(raw.y) * qsc;
            u32x2 packed = { h2u(lo), h2u(hi) };
            qb[tn] = __builtin_bit_cast(f16x4, packed);
            const unsigned char* rbase = Rel + h * 3072 + q * 48 + dgrp * 8;
            rb1[tn] = *(const f16x4*)rbase;
            rb2[tn] = *(const f16x4*)(rbase + 32);
        }
    }

    // ---- main loop over 9 key tiles, 2-deep ka/va prefetch ----
    f32x4 Oacc[4];
    float lsum[4];
    #pragma unroll
    for (int tn = 0; tn < 4; ++tn) { Oacc[tn] = (f32x4){0.f,0.f,0.f,0.f}; lsum[tn] = 0.f; }
    const f32x4 zf = {0.f, 0.f, 0.f, 0.f};
    const float SH = 3.0f * L2E;

    f16x4 kaA = *(const f16x4*)(Kl + h * 4608 + (l & 15) * 32 + dgrp * 8);
    f16x4 vaA = *(const f16x4*)(Vt + h * 4736 + (l & 15) * 296 + (dgrp * 4) * 2);

    #pragma unroll 1
    for (int tm = 0; tm < 9; ++tm) {
        int tmn = (tm + 1 < 9) ? tm + 1 : 0;
        f16x4 kaB = *(const f16x4*)(Kl + h * 4608 + (tmn * 16 + (l & 15)) * 32 + dgrp * 8);
        f16x4 vaB = *(const f16x4*)(Vt + h * 4736 + (l & 15) * 296 + (tmn * 16 + dgrp * 4) * 2);

        int key = tm * 16 + (l & 15);
        int kr = (key * 2731) >> 15;
        int kc = key - kr * 12;
        f16x4 oh1, oh2;
        #pragma unroll
        for (int i = 0; i < 4; ++i) {
            int a1 = 4 * dgrp + i;
            bool v1 = (a1 < 12) ? (kc == a1) : (kr == a1 - 12);
            oh1[i] = v1 ? (_Float16)1.0f : (_Float16)0.0f;
            int a2 = 16 + 4 * dgrp + i;
            bool v2 = (a2 < 24) && (kr == a2 - 12);
            oh2[i] = v2 ? (_Float16)1.0f : (_Float16)0.0f;
        }

        #pragma unroll
        for (int tn = 0; tn < 4; ++tn) {
            f32x4 s = __builtin_amdgcn_mfma_f32_16x16x16f16(kaA, qb[tn],  zf, 0, 0, 0);
            s       = __builtin_amdgcn_mfma_f32_16x16x16f16(oh1, rb1[tn], s,  0, 0, 0);
            s       = __builtin_amdgcn_mfma_f32_16x16x16f16(oh2, rb2[tn], s,  0, 0, 0);
            float e0 = exp2f(s[0] - SH);
            float e1 = exp2f(s[1] - SH);
            float e2 = exp2f(s[2] - SH);
            float e3 = exp2f(s[3] - SH);
            lsum[tn] += (e0 + e1) + (e2 + e3);
            u32x2 pp = { h2u(pkrtz(e0, e1)), h2u(pkrtz(e2, e3)) };
            f16x4 pb = __builtin_bit_cast(f16x4, pp);
            Oacc[tn] = __builtin_amdgcn_mfma_f32_16x16x16f16(vaA, pb, Oacc[tn], 0, 0, 0);
        }
        kaA = kaB; vaA = vaB;
    }

    // ---- normalize + write f16 to mldsh (aliases Kl) ----
    __syncthreads();
    #pragma unroll
    for (int tn = 0; tn < 4; ++tn) {
        float s = lsum[tn];
        s += __shfl_xor(s, 16);
        s += __shfl_xor(s, 32);
        float inv = 1.f / s;
        int q = tn * 16 + (l & 15);
        u32x2 w2 = { h2u(pkrtz(Oacc[tn][0] * inv, Oacc[tn][1] * inv)),
                     h2u(pkrtz(Oacc[tn][2] * inv, Oacc[tn][3] * inv)) };
        *(u32x2*)&mldsh[q][h * 16 + dgrp * 4] = w2;
    }
    __syncthreads();

    // ---- fused out-conv via MFMA: D[48oc x 64px] = w_out(f16) . mldsh ----
    {
        int tn2 = h;
        int pxl = tn2 * 16 + (l & 15);
        f16x4 bf[4];
        #pragma unroll
        for (int ks = 0; ks < 4; ++ks)
            bf[ks] = *(const f16x4*)&mldsh[pxl][ks * 16 + dgrp * 4];

        int gy = y0 + (pxl >> 3), gx = x0 + (pxl & 7);
        #pragma unroll
        for (int ot = 0; ot < 3; ++ot) {
            float4 bi = *(const float4*)(b_out + ot * 16 + dgrp * 4);
            f32x4 Cacc = { bi.x, bi.y, bi.z, bi.w };
            #pragma unroll
            for (int ks = 0; ks < 4; ++ks) {
                float4 wv = *(const float4*)(w_out + (ot * 16 + (l & 15)) * 64 + ks * 16 + dgrp * 4);
                Cacc = __builtin_amdgcn_mfma_f32_16x16x16f16(pk4(wv), bf[ks], Cacc, 0, 0, 0);
            }
            #pragma unroll
            for (int i = 0; i < 4; ++i)
                out[((size_t)(b * 48 + ot * 16 + dgrp * 4 + i)) * HWc + gy * Ww + gx] = Cacc[i];
        }
    }
}

// ---- K5b: easy windows — vs*sa (f16) + MFMA out-conv ----
__global__ __launch_bounds__(256) void k_easy(const float* __restrict__ vsb,
    const float* __restrict__ sab, const int* __restrict__ easyl,
    const float* __restrict__ w_out, const float* __restrict__ b_out,
    float* __restrict__ out)
{
    __shared__ __align__(16) _Float16 mldsh[64][72];   // 9216 B

    int tid = threadIdx.x;
    int blk = blockIdx.x;
    int b = blk / NKc;
    int n = easyl[blk];
    int hy = n / WNc, wx = n % WNc;
    int y0 = hy * 8, x0 = wx * 8;

    {
        int l = tid >> 2, part = tid & 3;
        int gy = y0 + (l >> 3), gx = x0 + (l & 7);
        const float* vp = vsb + ((size_t)(b * HWc) + gy * Ww + gx) * 64 + part * 16;
        float sv = sab[(size_t)b * HWc + gy * Ww + gx];
        #pragma unroll
        for (int j = 0; j < 4; ++j) {
            float4 v4 = *(const float4*)(vp + j * 4);
            u32x2 w2 = { h2u(pkrtz(v4.x * sv, v4.y * sv)),
                         h2u(pkrtz(v4.z * sv, v4.w * sv)) };
            *(u32x2*)&mldsh[l][part * 16 + j * 4] = w2;
        }
    }
    __syncthreads();

    {
        int l = tid & 63;
        int tn2 = __builtin_amdgcn_readfirstlane(tid >> 6);
        int dgrp = l >> 4;
        int pxl = tn2 * 16 + (l & 15);
        f16x4 bf[4];
        #pragma unroll
        for (int ks = 0; ks < 4; ++ks)
            bf[ks] = *(const f16x4*)&mldsh[pxl][ks * 16 + dgrp * 4];

        int gy = y0 + (pxl >> 3), gx = x0 + (pxl & 7);
        #pragma unroll
        for (int ot = 0; ot < 3; ++ot) {
            float4 bi = *(const float4*)(b_out + ot * 16 + dgrp * 4);
            f32x4 Cacc = { bi.x, bi.y, bi.z, bi.w };
            #pragma unroll
            for (int ks = 0; ks < 4; ++ks) {
                float4 wv = *(const float4*)(w_out + (ot * 16 + (l & 15)) * 64 + ks * 16 + dgrp * 4);
                Cacc = __builtin_amdgcn_mfma_f32_16x16x16f16(pk4(wv), bf[ks], Cacc, 0, 0, 0);
            }
            #pragma unroll
            for (int i = 0; i < 4; ++i)
                out[((size_t)(b * 48 + ot * 16 + dgrp * 4 + i)) * HWc + gy * Ww + gx] = Cacc[i];
        }
    }
}

extern "C" void kernel_launch(void* const* d_in, const int* in_sizes, int n_in,
                              void* d_out, int out_size, void* d_ws, size_t ws_size,
                              hipStream_t stream)
{
    const float* x    = (const float*)d_in[0];
    const float* cg   = (const float*)d_in[1];
    const float* wq   = (const float*)d_in[2];
    const float* bq   = (const float*)d_in[3];
    const float* wk   = (const float*)d_in[4];
    const float* bk   = (const float*)d_in[5];
    const float* wv   = (const float*)d_in[6];
    const float* bv   = (const float*)d_in[7];
    const float* w_in = (const float*)d_in[8];
    const float* b_in = (const float*)d_in[9];
    const float* ln_w = (const float*)d_in[10];
    const float* ln_b = (const float*)d_in[11];
    const float* w_sa = (const float*)d_in[12];
    const float* b_sa = (const float*)d_in[13];
    const float* w_m1 = (const float*)d_in[14];
    const float* b_m1 = (const float*)d_in[15];
    const float* w_m2 = (const float*)d_in[16];
    const float* b_m2 = (const float*)d_in[17];
    const float* rel_h= (const float*)d_in[18];
    const float* rel_w= (const float*)d_in[19];
    const float* w_out= (const float*)d_in[20];
    const float* b_out= (const float*)d_in[21];
    float* out = (float*)d_out;

    _Float16* qsh = (_Float16*)d_ws;
    _Float16* ksh = qsh + (size_t)Bc * 64 * HWc;
    float* vs   = (float*)(ksh + (size_t)Bc * 64 * HWc);
    float* sa   = vs + (size_t)Bc * 64 * HWc;
    float* mpix = sa + (size_t)Bc * HWc;
    int*   hardl= (int*)(mpix + (size_t)Bc * HWc);
    int*   easyl= hardl + Bc * NKc;

    k_qkv   <<<1152, 256, 0, stream>>>(x, wq, bq, wk, bk, wv, bv, qsh, ksh, vs);
    k_condsa<<<Bc * Hh, 192, 0, stream>>>(vs, cg, w_in, b_in, ln_w, ln_b, w_sa, b_sa, sa, mpix);
    k_score <<<4, 576, 0, stream>>>(mpix, w_m1, b_m1, w_m2, b_m2, hardl, easyl);
    k_easy  <<<1152, 256, 0, stream>>>(vs, sa, easyl, w_out, b_out, out);
    k_hard  <<<1152, 256, 0, stream>>>(qsh, ksh, vs, hardl, rel_h, rel_w, w_out, b_out, out);
}

// Round 21
// 171.778 us; speedup vs baseline: 1.2129x; 1.0242x over previous
//
#include <hip/hip_runtime.h>
#include <math.h>

#define Hh 192
#define Ww 192
#define HWc 36864
#define Bc 4
#define NWc 576
#define NKc 288
#define WNc 24

typedef _Float16 h2_t __attribute__((ext_vector_type(2)));
typedef _Float16 f16x4 __attribute__((ext_vector_type(4)));
typedef float f32x4 __attribute__((ext_vector_type(4)));
typedef unsigned u32x2 __attribute__((ext_vector_type(2)));
__device__ __forceinline__ h2_t u2h(unsigned u) { return __builtin_bit_cast(h2_t, u); }
__device__ __forceinline__ unsigned h2u(h2_t h) { return __builtin_bit_cast(unsigned, h); }
__device__ __forceinline__ h2_t pkrtz(float a, float b) {
    return __builtin_bit_cast(h2_t, __builtin_amdgcn_cvt_pkrtz(a, b));
}
__device__ __forceinline__ f16x4 pk4(float4 v) {
    u32x2 p = { h2u(pkrtz(v.x, v.y)), h2u(pkrtz(v.z, v.w)) };
    return __builtin_bit_cast(f16x4, p);
}
#define L2E 1.44269504f

// ---- K1: q/k/v 1x1 convs, layout [b][y][x][c] (unchanged from R20) ----
__global__ __launch_bounds__(256, 1) void k_qkv(const float* __restrict__ x,
    const float* __restrict__ wq, const float* __restrict__ bq,
    const float* __restrict__ wk, const float* __restrict__ bk,
    const float* __restrict__ wvw, const float* __restrict__ bv,
    _Float16* __restrict__ q, _Float16* __restrict__ k, float* __restrict__ v)
{
    __shared__ float xs[132][52];
    __shared__ __align__(16) unsigned char otile[17408];

    int tid = threadIdx.x;
    int blk = blockIdx.x;
    int b = blk / 288;
    int g0 = (blk % 288) * 128;
    const float* xb = x + (size_t)b * 48 * HWc + g0;

    #pragma unroll
    for (int it = 0; it < 6; ++it) {
        int i = it * 256 + tid;
        int c = i >> 5, p4 = (i & 31) * 4;
        float4 xv = *(const float4*)(xb + (size_t)c * HWc + p4);
        xs[p4 + 0][c] = xv.x; xs[p4 + 1][c] = xv.y;
        xs[p4 + 2][c] = xv.z; xs[p4 + 3][c] = xv.w;
    }

    int ln = tid & 63, wave = tid >> 6;
    int dgrp = ln >> 4;
    __syncthreads();

    size_t pbase = (size_t)b * HWc + g0;

    _Float16* qt = (_Float16*)otile;
    #pragma unroll 1
    for (int sel = 0; sel < 2; ++sel) {
        const float* W  = sel ? wk : wq;
        const float* Bi = sel ? bk : bq;
        _Float16* dst   = sel ? k : q;

        f16x4 A[4][3];
        float4 bf[4];
        #pragma unroll
        for (int ot = 0; ot < 4; ++ot) {
            #pragma unroll
            for (int ks = 0; ks < 3; ++ks)
                A[ot][ks] = pk4(*(const float4*)(W + (ot * 16 + (ln & 15)) * 48 + ks * 16 + dgrp * 4));
            bf[ot] = *(const float4*)(Bi + ot * 16 + dgrp * 4);
        }

        #pragma unroll
        for (int t2 = 0; t2 < 2; ++t2) {
            int px = (wave * 2 + t2) * 16 + (ln & 15);
            f16x4 Bf[3];
            #pragma unroll
            for (int ks = 0; ks < 3; ++ks)
                Bf[ks] = pk4(*(const float4*)&xs[px][ks * 16 + dgrp * 4]);
            #pragma unroll
            for (int ot = 0; ot < 4; ++ot) {
                f32x4 D = { bf[ot].x, bf[ot].y, bf[ot].z, bf[ot].w };
                #pragma unroll
                for (int ks = 0; ks < 3; ++ks)
                    D = __builtin_amdgcn_mfma_f32_16x16x16f16(A[ot][ks], Bf[ks], D, 0, 0, 0);
                u32x2 r2 = { h2u(pkrtz(D[0], D[1])), h2u(pkrtz(D[2], D[3])) };
                *(u32x2*)&qt[px * 68 + ot * 16 + dgrp * 4] = r2;
            }
        }
        __syncthreads();
        #pragma unroll
        for (int it = 0; it < 4; ++it) {
            int i = it * 256 + tid;
            int px = i >> 3, seg = i & 7;
            uint4 val = *(const uint4*)&qt[px * 68 + seg * 8];
            *(uint4*)(dst + (pbase + (size_t)px) * 64 + seg * 8) = val;
        }
        __syncthreads();
    }

    {
        f16x4 Avh[4][3], Avl[4][3];
        #pragma unroll
        for (int ot = 0; ot < 4; ++ot)
            #pragma unroll
            for (int ks = 0; ks < 3; ++ks) {
                float4 w4 = *(const float4*)(wvw + (ot * 16 + (ln & 15)) * 48 + ks * 16 + dgrp * 4);
                f16x4 wh = pk4(w4);
                float4 wr = make_float4(w4.x - (float)wh[0], w4.y - (float)wh[1],
                                        w4.z - (float)wh[2], w4.w - (float)wh[3]);
                Avh[ot][ks] = wh;
                Avl[ot][ks] = pk4(wr);
            }
        float4 bvf[4];
        #pragma unroll
        for (int ot = 0; ot < 4; ++ot) bvf[ot] = *(const float4*)(bv + ot * 16 + dgrp * 4);

        float* vt = (float*)otile;
        #pragma unroll 1
        for (int p = 0; p < 2; ++p) {
            int px = (p * 4 + wave) * 16 + (ln & 15);
            f16x4 Bh[3], Bl[3];
            #pragma unroll
            for (int ks = 0; ks < 3; ++ks) {
                float4 x4 = *(const float4*)&xs[px][ks * 16 + dgrp * 4];
                f16x4 xh = pk4(x4);
                float4 xr = make_float4(x4.x - (float)xh[0], x4.y - (float)xh[1],
                                        x4.z - (float)xh[2], x4.w - (float)xh[3]);
                Bh[ks] = xh;
                Bl[ks] = pk4(xr);
            }
            #pragma unroll
            for (int ot = 0; ot < 4; ++ot) {
                f32x4 D = { bvf[ot].x, bvf[ot].y, bvf[ot].z, bvf[ot].w };
                #pragma unroll
                for (int ks = 0; ks < 3; ++ks) {
                    D = __builtin_amdgcn_mfma_f32_16x16x16f16(Avh[ot][ks], Bh[ks], D, 0, 0, 0);
                    D = __builtin_amdgcn_mfma_f32_16x16x16f16(Avh[ot][ks], Bl[ks], D, 0, 0, 0);
                    D = __builtin_amdgcn_mfma_f32_16x16x16f16(Avl[ot][ks], Bh[ks], D, 0, 0, 0);
                }
                *(f32x4*)&vt[(px - p * 64) * 68 + ot * 16 + dgrp * 4] = D;
            }
            __syncthreads();
            #pragma unroll
            for (int it = 0; it < 4; ++it) {
                int i = it * 256 + tid;
                int px2 = i >> 4, seg = i & 15;
                float4 val = *(const float4*)&vt[px2 * 68 + seg * 4];
                *(float4*)(v + (pbase + (size_t)(p * 64 + px2)) * 64 + seg * 4) = val;
            }
            __syncthreads();
        }
    }
}

// -- K2: FUSED cond conv + LayerNorm + leaky + mpix + 3x3 conv + sigmoid --
__global__ __launch_bounds__(192) void k_condsa(const float* __restrict__ vs,
    const float* __restrict__ cg,
    const float* __restrict__ w_in, const float* __restrict__ b_in,
    const float* __restrict__ ln_w, const float* __restrict__ ln_b,
    const float* __restrict__ w_sa, const float* __restrict__ b_sa,
    float* __restrict__ sa, float* __restrict__ mpix)
{
    __shared__ float tl[3][17][194];

    int px = threadIdx.x;
    int blk = blockIdx.x;
    int b = blk / Hh;
    int y = blk % Hh;
    const float step = 2.0f / 7.0f;
    float gx_in = -1.0f + step * (float)(px & 7);

    #pragma unroll 1
    for (int r = 0; r < 3; ++r) {
        int yy = y - 1 + r;
        if ((unsigned)yy >= 192u) continue;
        size_t prem = (size_t)yy * Ww + px;

        float in[68];
        const float* vp = vs + ((size_t)b * HWc + prem) * 64;
        #pragma unroll
        for (int c = 0; c < 64; c += 4) {
            float4 t4 = *(const float4*)(vp + c);
            in[c] = t4.x; in[c+1] = t4.y; in[c+2] = t4.z; in[c+3] = t4.w;
        }
        in[64] = cg[((size_t)b * 2 + 0) * HWc + prem];
        in[65] = cg[((size_t)b * 2 + 1) * HWc + prem];
        in[66] = -1.0f + step * (float)(yy & 7);
        in[67] = gx_in;

        float tv[17];
        float mu = 0.f;
        #pragma unroll
        for (int o = 0; o < 17; ++o) {
            float a = b_in[o];
            const float* wr = w_in + o * 68;
            #pragma unroll
            for (int c = 0; c < 68; ++c) a = fmaf(in[c], wr[c], a);
            tv[o] = a;
            mu += a;
        }
        mu *= (1.f / 17.f);
        float var = 0.f;
        #pragma unroll
        for (int o = 0; o < 17; ++o) { float d = tv[o] - mu; var = fmaf(d, d, var); }
        var *= (1.f / 17.f);
        float rstd = 1.f / sqrtf(var + 1e-6f);

        float msum = 0.f;
        #pragma unroll
        for (int o = 0; o < 17; ++o) {
            float z = (tv[o] - mu) * rstd * ln_w[o] + ln_b[o];
            z = (z >= 0.f) ? z : 0.1f * z;
            tl[r][o][px] = z;
            msum += z;
        }
        if (r == 1) mpix[(size_t)b * HWc + prem] = msum * (1.f / 17.f);
    }
    __syncthreads();

    float a = b_sa[0];
    #pragma unroll 1
    for (int c = 0; c < 17; ++c) {
        const float* wr = w_sa + c * 9;
        #pragma unroll
        for (int ki = 0; ki < 3; ++ki) {
            int yy = y + ki - 1;
            if ((unsigned)yy >= 192u) continue;
            #pragma unroll
            for (int kj = 0; kj < 3; ++kj) {
                int xc = px + kj - 1;
                if ((unsigned)xc >= 192u) continue;
                a = fmaf(tl[ki][c][xc], wr[ki * 3 + kj], a);
            }
        }
    }
    sa[(size_t)b * HWc + (size_t)y * Ww + px] = 1.f / (1.f + expf(-a));
}

// -- K4: window score MLP + stable descending rank -> compacted lists --
__global__ __launch_bounds__(576) void k_score(const float* __restrict__ mpix,
    const float* __restrict__ w_m1, const float* __restrict__ b_m1,
    const float* __restrict__ w_m2, const float* __restrict__ b_m2,
    int* __restrict__ hardl, int* __restrict__ easyl)
{
    __shared__ float sc[NWc];
    int b = blockIdx.x;
    int w = threadIdx.x;
    {
        int hy = w / WNc, wx = w % WNc;
        const float* mp = mpix + (size_t)b * HWc + (hy * 8) * Ww + wx * 8;
        float m[64];
        #pragma unroll
        for (int l = 0; l < 64; ++l) m[l] = mp[(l >> 3) * Ww + (l & 7)];
        float h1[8];
        #pragma unroll
        for (int j = 0; j < 8; ++j) {
            float a = b_m1[j];
            const float* wr = w_m1 + j * 64;
            #pragma unroll
            for (int l = 0; l < 64; ++l) a = fmaf(m[l], wr[l], a);
            h1[j] = (a >= 0.f) ? a : 0.1f * a;
        }
        float l0 = b_m2[0], l1 = b_m2[1];
        #pragma unroll
        for (int j = 0; j < 8; ++j) {
            l0 = fmaf(h1[j], w_m2[j], l0);
            l1 = fmaf(h1[j], w_m2[8 + j], l1);
        }
        float mx = fmaxf(l0, l1);
        float e0 = expf(l0 - mx), e1 = expf(l1 - mx);
        sc[w] = e0 / (e0 + e1);
    }
    __syncthreads();
    float s = sc[w];
    int cnt = 0;
    for (int w2 = 0; w2 < NWc; ++w2) {
        float s2 = sc[w2];
        cnt += ((s2 > s) || (s2 == s && w2 < w)) ? 1 : 0;
    }
    if (cnt < NKc) hardl[b * NKc + cnt] = w;
    else           easyl[b * NKc + (cnt - NKc)] = w;
}

// ---- K5: merged window kernel. Blocks [0,1152): hard (MFMA flash attn,
// rel via intra-wave shuffles — no Rel LDS -> 37.4KB -> 4 blocks/CU).
// Blocks [1152,2304): easy (vs*sa + MFMA out-conv). One launch.
__global__ __launch_bounds__(256) void k_win(const _Float16* __restrict__ qs,
    const _Float16* __restrict__ ks, const float* __restrict__ vsb,
    const float* __restrict__ sab,
    const int* __restrict__ hardl, const int* __restrict__ easyl,
    const float* __restrict__ relh, const float* __restrict__ relw,
    const float* __restrict__ w_out, const float* __restrict__ b_out,
    float* __restrict__ out)
{
    __shared__ __align__(16) unsigned char smem[37376];
    unsigned char* Kl = smem;               // [4][144][32B], 18432 B
    unsigned char* Vt = smem + 18432;       // [4][16 d][148 k] f16, 18944 B
    _Float16 (*mldsh)[72] = (_Float16 (*)[72])smem;  // 9216 B, aliases Kl

    int tid = threadIdx.x;
    int blk = blockIdx.x;
    int l = tid & 63;
    int dgrp = l >> 4;

    if (blk >= Bc * NKc) {
        // ---------------- easy path ----------------
        int blk2 = blk - Bc * NKc;
        int b = blk2 / NKc;
        int n = easyl[blk2];
        int hy = n / WNc, wx = n % WNc;
        int y0 = hy * 8, x0 = wx * 8;

        {
            int lp = tid >> 2, part = tid & 3;
            int gy = y0 + (lp >> 3), gx = x0 + (lp & 7);
            const float* vp = vsb + ((size_t)(b * HWc) + gy * Ww + gx) * 64 + part * 16;
            float sv = sab[(size_t)b * HWc + gy * Ww + gx];
            #pragma unroll
            for (int j = 0; j < 4; ++j) {
                float4 v4 = *(const float4*)(vp + j * 4);
                u32x2 w2 = { h2u(pkrtz(v4.x * sv, v4.y * sv)),
                             h2u(pkrtz(v4.z * sv, v4.w * sv)) };
                *(u32x2*)&mldsh[lp][part * 16 + j * 4] = w2;
            }
        }
        __syncthreads();
        {
            int tn2 = __builtin_amdgcn_readfirstlane(tid >> 6);
            int pxl = tn2 * 16 + (l & 15);
            f16x4 bfr[4];
            #pragma unroll
            for (int ksi = 0; ksi < 4; ++ksi)
                bfr[ksi] = *(const f16x4*)&mldsh[pxl][ksi * 16 + dgrp * 4];

            int gy = y0 + (pxl >> 3), gx = x0 + (pxl & 7);
            #pragma unroll
            for (int ot = 0; ot < 3; ++ot) {
                float4 bi = *(const float4*)(b_out + ot * 16 + dgrp * 4);
                f32x4 Cacc = { bi.x, bi.y, bi.z, bi.w };
                #pragma unroll
                for (int ksi = 0; ksi < 4; ++ksi) {
                    float4 wv = *(const float4*)(w_out + (ot * 16 + (l & 15)) * 64 + ksi * 16 + dgrp * 4);
                    Cacc = __builtin_amdgcn_mfma_f32_16x16x16f16(pk4(wv), bfr[ksi], Cacc, 0, 0, 0);
                }
                #pragma unroll
                for (int i = 0; i < 4; ++i)
                    out[((size_t)(b * 48 + ot * 16 + dgrp * 4 + i)) * HWc + gy * Ww + gx] = Cacc[i];
            }
        }
        return;
    }

    // ---------------- hard path ----------------
    int b = blk / NKc;
    int n = hardl[blk];
    int hy = n / WNc, wx = n % WNc;
    int y0 = hy * 8, x0 = wx * 8;

    // ---- stage K (f16 copy) and V (f32->f16, d-major, 148-padded), zero OOB ----
    #pragma unroll
    for (int i = 0; i < 9; ++i) {
        int idx = i * 256 + tid;
        int px = idx >> 4, c4 = idx & 15;
        int py = px / 12, pxx = px - py * 12;
        int ky = y0 - 2 + py, kx = x0 - 2 + pxx;
        bool ok = ((unsigned)ky < 192u) && ((unsigned)kx < 192u);
        int kyc = min(max(ky, 0), 191), kxc = min(max(kx, 0), 191);
        size_t poff = ((size_t)(b * HWc) + kyc * Ww + kxc) * 64 + c4 * 4;
        uint2 k2 = *(const uint2*)(ks + poff);
        float4 v4 = *(const float4*)(vsb + poff);
        if (!ok) { k2 = make_uint2(0, 0); v4 = make_float4(0, 0, 0, 0); }
        int hd = c4 >> 2, d0 = (c4 & 3) * 4;
        *(uint2*)(Kl + hd * 4608 + px * 32 + (c4 & 3) * 8) = k2;
        _Float16* vh = (_Float16*)(Vt + hd * 4736);
        vh[(d0 + 0) * 148 + px] = (_Float16)v4.x;
        vh[(d0 + 1) * 148 + px] = (_Float16)v4.y;
        vh[(d0 + 2) * 148 + px] = (_Float16)v4.z;
        vh[(d0 + 3) * 148 + px] = (_Float16)v4.w;
    }

    int h = __builtin_amdgcn_readfirstlane(tid >> 6);  // head (wave-uniform)

    // ---- rel values for own query l (log2e-scaled), kept in registers ----
    unsigned rr[12];
    {
        int qr = l >> 3, qc = l & 7;
        const _Float16* qp = qs + ((size_t)(b * HWc) + (y0 + qr) * Ww + (x0 + qc)) * 64 + h * 16;
        uint4 q0 = *(const uint4*)qp;
        uint4 q1 = *(const uint4*)(qp + 8);
        h2_t qhp[8] = { u2h(q0.x), u2h(q0.y), u2h(q0.z), u2h(q0.w),
                        u2h(q1.x), u2h(q1.y), u2h(q1.z), u2h(q1.w) };
        float qv[16];
        #pragma unroll
        for (int j = 0; j < 8; ++j) { qv[2*j] = (float)qhp[j].x; qv[2*j+1] = (float)qhp[j].y; }

        float rw[12], rh[12];
        #pragma unroll
        for (int kc = 0; kc < 12; ++kc) {
            const float* rp = relw + (kc - qc + 11) * 16;
            float a = 0.f;
            #pragma unroll
            for (int j = 0; j < 4; ++j) {
                float4 t4 = *(const float4*)(rp + j * 4);
                a = fmaf(qv[j*4+0], t4.x, a); a = fmaf(qv[j*4+1], t4.y, a);
                a = fmaf(qv[j*4+2], t4.z, a); a = fmaf(qv[j*4+3], t4.w, a);
            }
            rw[kc] = a;
        }
        #pragma unroll
        for (int kr = 0; kr < 12; ++kr) {
            const float* rp = relh + (kr - qr + 11) * 16;
            float a = 0.f;
            #pragma unroll
            for (int j = 0; j < 4; ++j) {
                float4 t4 = *(const float4*)(rp + j * 4);
                a = fmaf(qv[j*4+0], t4.x, a); a = fmaf(qv[j*4+1], t4.y, a);
                a = fmaf(qv[j*4+2], t4.z, a); a = fmaf(qv[j*4+3], t4.w, a);
            }
            rh[kr] = a;
        }
        #pragma unroll
        for (int j = 0; j < 6; ++j) rr[j]     = h2u(pkrtz(L2E * rw[2*j], L2E * rw[2*j+1]));
        #pragma unroll
        for (int j = 0; j < 6; ++j) rr[6 + j] = h2u(pkrtz(L2E * rh[2*j], L2E * rh[2*j+1]));
    }

    // ---- B-fragments: Q scaled by 0.25*log2e; rel via intra-wave shuffles ----
    f16x4 qb[4], rb1[4], rb2[4];
    {
        const h2_t qsc = { (_Float16)(0.25f * L2E), (_Float16)(0.25f * L2E) };
        #pragma unroll
        for (int tn = 0; tn < 4; ++tn) {
            int qq = tn * 16 + (l & 15);
            int qr = qq >> 3, qc = qq & 7;
            uint2 raw = *(const uint2*)(qs + ((size_t)(b * HWc) + (y0 + qr) * Ww + (x0 + qc)) * 64 + h * 16 + dgrp * 4);
            h2_t lo = u2h(raw.x) * qsc, hi = u2h(raw.y) * qsc;
            u32x2 packed = { h2u(lo), h2u(hi) };
            qb[tn] = __builtin_bit_cast(f16x4, packed);

            unsigned s[12];
            #pragma unroll
            for (int j = 0; j < 12; ++j) s[j] = (unsigned)__shfl((int)rr[j], qq);
            unsigned a0 = (dgrp == 0) ? s[0] : (dgrp == 1) ? s[2] : (dgrp == 2) ? s[4] : s[6];
            unsigned a1 = (dgrp == 0) ? s[1] : (dgrp == 1) ? s[3] : (dgrp == 2) ? s[5] : s[7];
            unsigned b0 = (dgrp == 0) ? s[8] : (dgrp == 1) ? s[10] : 0u;
            unsigned b1 = (dgrp == 0) ? s[9] : (dgrp == 1) ? s[11] : 0u;
            u32x2 p1 = { a0, a1 };
            u32x2 p2 = { b0, b1 };
            rb1[tn] = __builtin_bit_cast(f16x4, p1);
            rb2[tn] = __builtin_bit_cast(f16x4, p2);
        }
    }
    __syncthreads();   // Kl/Vt staged

    // ---- main loop over 9 key tiles, 2-deep ka/va prefetch ----
    f32x4 Oacc[4];
    float lsum[4];
    #pragma unroll
    for (int tn = 0; tn < 4; ++tn) { Oacc[tn] = (f32x4){0.f,0.f,0.f,0.f}; lsum[tn] = 0.f; }
    const f32x4 zf = {0.f, 0.f, 0.f, 0.f};
    const float SH = 3.0f * L2E;

    f16x4 kaA = *(const f16x4*)(Kl + h * 4608 + (l & 15) * 32 + dgrp * 8);
    f16x4 vaA = *(const f16x4*)(Vt + h * 4736 + (l & 15) * 296 + (dgrp * 4) * 2);

    #pragma unroll 1
    for (int tm = 0; tm < 9; ++tm) {
        int tmn = (tm + 1 < 9) ? tm + 1 : 0;
        f16x4 kaB = *(const f16x4*)(Kl + h * 4608 + (tmn * 16 + (l & 15)) * 32 + dgrp * 8);
        f16x4 vaB = *(const f16x4*)(Vt + h * 4736 + (l & 15) * 296 + (tmn * 16 + dgrp * 4) * 2);

        int key = tm * 16 + (l & 15);
        int kr = (key * 2731) >> 15;
        int kc = key - kr * 12;
        f16x4 oh1, oh2;
        #pragma unroll
        for (int i = 0; i < 4; ++i) {
            int a1 = 4 * dgrp + i;
            bool v1 = (a1 < 12) ? (kc == a1) : (kr == a1 - 12);
            oh1[i] = v1 ? (_Float16)1.0f : (_Float16)0.0f;
            int a2 = 16 + 4 * dgrp + i;
            bool v2 = (a2 < 24) && (kr == a2 - 12);
            oh2[i] = v2 ? (_Float16)1.0f : (_Float16)0.0f;
        }

        #pragma unroll
        for (int tn = 0; tn < 4; ++tn) {
            f32x4 s = __builtin_amdgcn_mfma_f32_16x16x16f16(kaA, qb[tn],  zf, 0, 0, 0);
            s       = __builtin_amdgcn_mfma_f32_16x16x16f16(oh1, rb1[tn], s,  0, 0, 0);
            s       = __builtin_amdgcn_mfma_f32_16x16x16f16(oh2, rb2[tn], s,  0, 0, 0);
            float e0 = exp2f(s[0] - SH);
            float e1 = exp2f(s[1] - SH);
            float e2 = exp2f(s[2] - SH);
            float e3 = exp2f(s[3] - SH);
            lsum[tn] += (e0 + e1) + (e2 + e3);
            u32x2 pp = { h2u(pkrtz(e0, e1)), h2u(pkrtz(e2, e3)) };
            f16x4 pb = __builtin_bit_cast(f16x4, pp);
            Oacc[tn] = __builtin_amdgcn_mfma_f32_16x16x16f16(vaA, pb, Oacc[tn], 0, 0, 0);
        }
        kaA = kaB; vaA = vaB;
    }

    // ---- normalize + write f16 to mldsh (aliases Kl) ----
    __syncthreads();
    #pragma unroll
    for (int tn = 0; tn < 4; ++tn) {
        float s = lsum[tn];
        s += __shfl_xor(s, 16);
        s += __shfl_xor(s, 32);
        float inv = 1.f / s;
        int qq = tn * 16 + (l & 15);
        u32x2 w2 = { h2u(pkrtz(Oacc[tn][0] * inv, Oacc[tn][1] * inv)),
                     h2u(pkrtz(Oacc[tn][2] * inv, Oacc[tn][3] * inv)) };
        *(u32x2*)&mldsh[qq][h * 16 + dgrp * 4] = w2;
    }
    __syncthreads();

    // ---- fused out-conv via MFMA: D[48oc x 64px] = w_out(f16) . mldsh ----
    {
        int pxl = h * 16 + (l & 15);
        f16x4 bfr[4];
        #pragma unroll
        for (int ksi = 0; ksi < 4; ++ksi)
            bfr[ksi] = *(const f16x4*)&mldsh[pxl][ksi * 16 + dgrp * 4];

        int gy = y0 + (pxl >> 3), gx = x0 + (pxl & 7);
        #pragma unroll
        for (int ot = 0; ot < 3; ++ot) {
            float4 bi = *(const float4*)(b_out + ot * 16 + dgrp * 4);
            f32x4 Cacc = { bi.x, bi.y, bi.z, bi.w };
            #pragma unroll
            for (int ksi = 0; ksi < 4; ++ksi) {
                float4 wv = *(const float4*)(w_out + (ot * 16 + (l & 15)) * 64 + ksi * 16 + dgrp * 4);
                Cacc = __builtin_amdgcn_mfma_f32_16x16x16f16(pk4(wv), bfr[ksi], Cacc, 0, 0, 0);
            }
            #pragma unroll
            for (int i = 0; i < 4; ++i)
                out[((size_t)(b * 48 + ot * 16 + dgrp * 4 + i)) * HWc + gy * Ww + gx] = Cacc[i];
        }
    }
}

extern "C" void kernel_launch(void* const* d_in, const int* in_sizes, int n_in,
                              void* d_out, int out_size, void* d_ws, size_t ws_size,
                              hipStream_t stream)
{
    const float* x    = (const float*)d_in[0];
    const float* cg   = (const float*)d_in[1];
    const float* wq   = (const float*)d_in[2];
    const float* bq   = (const float*)d_in[3];
    const float* wk   = (const float*)d_in[4];
    const float* bk   = (const float*)d_in[5];
    const float* wv   = (const float*)d_in[6];
    const float* bv   = (const float*)d_in[7];
    const float* w_in = (const float*)d_in[8];
    const float* b_in = (const float*)d_in[9];
    const float* ln_w = (const float*)d_in[10];
    const float* ln_b = (const float*)d_in[11];
    const float* w_sa = (const float*)d_in[12];
    const float* b_sa = (const float*)d_in[13];
    const float* w_m1 = (const float*)d_in[14];
    const float* b_m1 = (const float*)d_in[15];
    const float* w_m2 = (const float*)d_in[16];
    const float* b_m2 = (const float*)d_in[17];
    const float* rel_h= (const float*)d_in[18];
    const float* rel_w= (const float*)d_in[19];
    const float* w_out= (const float*)d_in[20];
    const float* b_out= (const float*)d_in[21];
    float* out = (float*)d_out;

    _Float16* qsh = (_Float16*)d_ws;
    _Float16* ksh = qsh + (size_t)Bc * 64 * HWc;
    float* vs   = (float*)(ksh + (size_t)Bc * 64 * HWc);
    float* sa   = vs + (size_t)Bc * 64 * HWc;
    float* mpix = sa + (size_t)Bc * HWc;
    int*   hardl= (int*)(mpix + (size_t)Bc * HWc);
    int*   easyl= hardl + Bc * NKc;

    k_qkv   <<<1152, 256, 0, stream>>>(x, wq, bq, wk, bk, wv, bv, qsh, ksh, vs);
    k_condsa<<<Bc * Hh, 192, 0, stream>>>(vs, cg, w_in, b_in, ln_w, ln_b, w_sa, b_sa, sa, mpix);
    k_score <<<4, 576, 0, stream>>>(mpix, w_m1, b_m1, w_m2, b_m2, hardl, easyl);
    k_win   <<<2 * Bc * NKc, 256, 0, stream>>>(qsh, ksh, vs, sa, hardl, easyl,
                                               rel_h, rel_w, w_out, b_out, out);
}